// Round 6
// baseline (592.561 us; speedup 1.0000x reference)
//
#include <hip/hip_runtime.h>

#define DIM 128
#define N_GRAPHS 64
#define LDSP 132  // padded LDS row stride (floats): +4 breaks 16-way bank conflict

typedef __attribute__((ext_vector_type(4))) float f32x4;
typedef __attribute__((ext_vector_type(8))) short s16x8;

// ---------------- degree / CSR precompute ----------------

__global__ void k_count(const int* __restrict__ col, int* __restrict__ cnt, int e) {
    int i = blockIdx.x * blockDim.x + threadIdx.x;
    if (i < e) atomicAdd(&cnt[col[i]], 1);
}

__global__ void k_make_dis(const int* __restrict__ cnt, float* __restrict__ dis, int n) {
    int i = blockIdx.x * blockDim.x + threadIdx.x;
    if (i < n) dis[i] = rsqrtf(1.0f + (float)cnt[i]);
}

__global__ __launch_bounds__(256) void k_bsum(const int* __restrict__ cnt,
                                              int* __restrict__ bsum, int n) {
    __shared__ int s[256];
    int t = threadIdx.x;
    int i = blockIdx.x * 256 + t;
    s[t] = (i < n) ? cnt[i] : 0;
    __syncthreads();
    for (int o = 128; o > 0; o >>= 1) {
        if (t < o) s[t] += s[t + o];
        __syncthreads();
    }
    if (t == 0) bsum[blockIdx.x] = s[0];
}

__global__ __launch_bounds__(256) void k_bscan(const int* __restrict__ bsum,
                                               int* __restrict__ bbase, int nb) {
    __shared__ int s[256];
    int t = threadIdx.x;
    int v = (t < nb) ? bsum[t] : 0;
    s[t] = v;
    __syncthreads();
    for (int o = 1; o < 256; o <<= 1) {
        int u = (t >= o) ? s[t - o] : 0;
        __syncthreads();
        s[t] += u;
        __syncthreads();
    }
    if (t < nb) bbase[t] = s[t] - v;  // exclusive
}

__global__ __launch_bounds__(256) void k_bfinal(const int* __restrict__ cnt,
        const int* __restrict__ bbase, int* __restrict__ rowptr,
        int* __restrict__ cursor, int n, int e) {
    __shared__ int s[256];
    int t = threadIdx.x;
    int i = blockIdx.x * 256 + t;
    int v = (i < n) ? cnt[i] : 0;
    s[t] = v;
    __syncthreads();
    for (int o = 1; o < 256; o <<= 1) {
        int u = (t >= o) ? s[t - o] : 0;
        __syncthreads();
        s[t] += u;
        __syncthreads();
    }
    if (i < n) {
        int excl = s[t] - v + bbase[blockIdx.x];
        rowptr[i] = excl;
        cursor[i] = excl;
        if (i == n - 1) rowptr[n] = e;
    }
}

__global__ void k_fill(const int* __restrict__ row, const int* __restrict__ col,
                       int* __restrict__ cursor, int* __restrict__ csr_src, int e) {
    int i = blockIdx.x * blockDim.x + threadIdx.x;
    if (i >= e) return;
    int pos = atomicAdd(&cursor[col[i]], 1);
    csr_src[pos] = row[i];
}

// ---------------- bf16 helpers ----------------

__device__ __forceinline__ unsigned short bf16_rtne(float f) {
    unsigned u = __builtin_bit_cast(unsigned, f);
    unsigned r = u + 0x7FFFu + ((u >> 16) & 1u);
    return (unsigned short)(r >> 16);
}
__device__ __forceinline__ float bf16_to_f32(unsigned short h) {
    unsigned u = ((unsigned)h) << 16;
    return __builtin_bit_cast(float, u);
}

// W[k][c] (128x128 f32) -> Wt_hi[c][k], Wt_lo[c][k] (bf16 split)
__global__ __launch_bounds__(256) void k_wprep(const float* __restrict__ W,
        unsigned short* __restrict__ wt_hi, unsigned short* __restrict__ wt_lo) {
    int i = blockIdx.x * 256 + threadIdx.x;  // 16384 total
    int k = i >> 7, c = i & 127;
    float w = W[i];
    unsigned short h = bf16_rtne(w);
    unsigned short l = bf16_rtne(w - bf16_to_f32(h));
    wt_hi[c * DIM + k] = h;
    wt_lo[c * DIM + k] = l;
}

// ---------------- fused layer: aggregate 64 rows into LDS, then MFMA ----------------
// phase 1: wave-per-node gather aggregation (as k_gcn_agg) -> sA[64][LDSP]
// phase 2: out[r][:] = relu(aggA[r][:] @ W + b) via 3-term bf16-split MFMA
//   mfma_f32_16x16x32_bf16: A row=lane&15, k=(lane>>4)*8+j ; C col=lane&15, row=(lane>>4)*4+reg

__global__ __launch_bounds__(256) void k_gcn_fused(const float* __restrict__ in,
        const int* __restrict__ csr_src, const int* __restrict__ rowptr,
        const float* __restrict__ dis,
        const unsigned short* __restrict__ wt_hi, const unsigned short* __restrict__ wt_lo,
        const float* __restrict__ bias, float* __restrict__ out, int n) {
    __shared__ float sA[64 * LDSP];  // 33.8 KB
    int tid = threadIdx.x;
    int wave = tid >> 6, lane = tid & 63;
    int blk = blockIdx.x;
    const int coff = lane * 2;

    // ---- phase 1: aggregation into LDS ----
    for (int i = wave; i < 64; i += 4) {
        int wid = blk * 64 + i;
        float2 acc = {0.f, 0.f};
        if (wid < n) {
            float d = dis[wid];
            acc = *(const float2*)&in[(size_t)wid * DIM + coff];
            float dd = d * d;  // self-loop weight
            acc.x *= dd; acc.y *= dd;
            int p = rowptr[wid], p1 = rowptr[wid + 1];
            for (; p + 3 < p1; p += 4) {
                int s0 = csr_src[p], s1 = csr_src[p + 1], s2 = csr_src[p + 2], s3 = csr_src[p + 3];
                float w0 = d * dis[s0], w1 = d * dis[s1], w2 = d * dis[s2], w3 = d * dis[s3];
                float2 v0 = *(const float2*)&in[(size_t)s0 * DIM + coff];
                float2 v1 = *(const float2*)&in[(size_t)s1 * DIM + coff];
                float2 v2 = *(const float2*)&in[(size_t)s2 * DIM + coff];
                float2 v3 = *(const float2*)&in[(size_t)s3 * DIM + coff];
                acc.x += v0.x * w0; acc.y += v0.y * w0;
                acc.x += v1.x * w1; acc.y += v1.y * w1;
                acc.x += v2.x * w2; acc.y += v2.y * w2;
                acc.x += v3.x * w3; acc.y += v3.y * w3;
            }
            for (; p < p1; p++) {
                int s = csr_src[p];
                float w = d * dis[s];
                float2 v = *(const float2*)&in[(size_t)s * DIM + coff];
                acc.x += v.x * w;
                acc.y += v.y * w;
            }
        }
        *(float2*)&sA[i * LDSP + coff] = acc;
    }
    __syncthreads();

    // ---- phase 2: MFMA matmul from LDS ----
    int lrow = lane & 15;   // A-frag row within 16-row tile / C col index
    int lk = lane >> 4;     // k-group 0..3
    int r0 = blk * 64 + wave * 16;
    int rib = wave * 16 + lrow;

    s16x8 ah[4], al[4];
#pragma unroll
    for (int ks = 0; ks < 4; ks++) {
        int kb = ks * 32 + lk * 8;
        float4 u0 = *(const float4*)&sA[rib * LDSP + kb];
        float4 u1 = *(const float4*)&sA[rib * LDSP + kb + 4];
        float v[8] = {u0.x, u0.y, u0.z, u0.w, u1.x, u1.y, u1.z, u1.w};
        s16x8 h, l;
#pragma unroll
        for (int j = 0; j < 8; j++) {
            unsigned short hb = bf16_rtne(v[j]);
            h[j] = (short)hb;
            l[j] = (short)bf16_rtne(v[j] - bf16_to_f32(hb));
        }
        ah[ks] = h; al[ks] = l;
    }

    f32x4 acc[8];
#pragma unroll
    for (int ct = 0; ct < 8; ct++) {
        const unsigned short* bh_base = wt_hi + (size_t)(ct * 16 + lrow) * DIM + lk * 8;
        const unsigned short* bl_base = wt_lo + (size_t)(ct * 16 + lrow) * DIM + lk * 8;
        s16x8 bh[4], bl[4];
#pragma unroll
        for (int ks = 0; ks < 4; ks++) {
            bh[ks] = *(const s16x8*)(bh_base + ks * 32);
            bl[ks] = *(const s16x8*)(bl_base + ks * 32);
        }
        f32x4 c = {0.f, 0.f, 0.f, 0.f};
#pragma unroll
        for (int ks = 0; ks < 4; ks++) {
            c = __builtin_amdgcn_mfma_f32_16x16x32_bf16(ah[ks], bh[ks], c, 0, 0, 0);
            c = __builtin_amdgcn_mfma_f32_16x16x32_bf16(al[ks], bh[ks], c, 0, 0, 0);
            c = __builtin_amdgcn_mfma_f32_16x16x32_bf16(ah[ks], bl[ks], c, 0, 0, 0);
        }
        acc[ct] = c;
    }

#pragma unroll
    for (int ct = 0; ct < 8; ct++) {
        int col = ct * 16 + lrow;
        float bcol = bias[col];
#pragma unroll
        for (int reg = 0; reg < 4; reg++) {
            int orow = r0 + lk * 4 + reg;
            if (orow < n) {
                float v = acc[ct][reg] + bcol;
                out[(size_t)orow * DIM + col] = v > 0.f ? v : 0.f;
            }
        }
    }
}

// ---------------- global mean pool: two-phase, device-filling ----------------
// phase A: 16 slices x 64 graphs = 1024 blocks -> partial sums
__global__ __launch_bounds__(256) void k_pool_part(const float* __restrict__ h,
        const int* __restrict__ batch, float* __restrict__ part, int n) {
    int g = blockIdx.x >> 4, s = blockIdx.x & 15;
    int lo = 0, hi = n;
    while (lo < hi) { int m = (lo + hi) >> 1; if (batch[m] < g) lo = m + 1; else hi = m; }
    int start = lo;
    int lo2 = start, hi2 = n;
    while (lo2 < hi2) { int m = (lo2 + hi2) >> 1; if (batch[m] < g + 1) lo2 = m + 1; else hi2 = m; }
    int end = lo2;

    int t = threadIdx.x;
    int wave = t >> 6, lane = t & 63;
    float2 acc = {0.f, 0.f};
    for (int r = start + s + 16 * wave; r < end; r += 64) {
        float2 v = *(const float2*)&h[(size_t)r * DIM + lane * 2];
        acc.x += v.x; acc.y += v.y;
    }
    __shared__ float2 red[4][64];
    red[wave][lane] = acc;
    __syncthreads();
    if (t < 64) {
        float2 s0 = red[0][t], s1 = red[1][t], s2 = red[2][t], s3 = red[3][t];
        float2 o;
        o.x = s0.x + s1.x + s2.x + s3.x;
        o.y = s0.y + s1.y + s2.y + s3.y;
        *(float2*)&part[(size_t)blockIdx.x * DIM + t * 2] = o;
    }
}

// phase B: 64 blocks x 128 threads: combine 16 partials, divide by count
__global__ __launch_bounds__(128) void k_pool_fin(const float* __restrict__ part,
        const int* __restrict__ batch, float* __restrict__ out, int n) {
    int g = blockIdx.x, c = threadIdx.x;
    int lo = 0, hi = n;
    while (lo < hi) { int m = (lo + hi) >> 1; if (batch[m] < g) lo = m + 1; else hi = m; }
    int start = lo;
    int lo2 = start, hi2 = n;
    while (lo2 < hi2) { int m = (lo2 + hi2) >> 1; if (batch[m] < g + 1) lo2 = m + 1; else hi2 = m; }
    int end = lo2;

    float s = 0.f;
#pragma unroll
    for (int k = 0; k < 16; k++) s += part[(size_t)(g * 16 + k) * DIM + c];
    float cnt = (float)(end - start);
    cnt = cnt > 1.f ? cnt : 1.f;
    out[g * DIM + c] = s / cnt;
}

// ---------------- launch ----------------

extern "C" void kernel_launch(void* const* d_in, const int* in_sizes, int n_in,
                              void* d_out, int out_size, void* d_ws, size_t ws_size,
                              hipStream_t stream) {
    const float* x  = (const float*)d_in[0];
    const int*   ei = (const int*)d_in[1];
    const int*   batch = (const int*)d_in[2];
    const float* W1 = (const float*)d_in[3];
    const float* b1 = (const float*)d_in[4];
    const float* W2 = (const float*)d_in[5];
    const float* b2 = (const float*)d_in[6];
    const float* W3 = (const float*)d_in[7];
    const float* b3 = (const float*)d_in[8];

    int n = in_sizes[0] / DIM;  // 50000
    int e = in_sizes[1] / 2;    // 800000
    const int* erow = ei;       // sources
    const int* ecol = ei + e;   // targets
    int nb = (n + 255) / 256;   // 196 scan blocks (<=256 required)

    char* ws = (char*)d_ws;
    size_t off = 0;
    auto alloc = [&](size_t bytes) -> void* {
        void* p = (void*)(ws + off);
        off += (bytes + 255) & ~(size_t)255;
        return p;
    };
    float* dis     = (float*)alloc((size_t)n * 4);
    int*   rowptr  = (int*)alloc((size_t)(n + 1) * 4);
    int*   csr_src = (int*)alloc((size_t)e * 4);
    float* bufA    = (float*)alloc((size_t)n * DIM * 4);
    float* bufB    = (float*)alloc((size_t)n * DIM * 4);
    unsigned short* wt_hi1 = (unsigned short*)alloc(DIM * DIM * 2);
    unsigned short* wt_lo1 = (unsigned short*)alloc(DIM * DIM * 2);
    unsigned short* wt_hi2 = (unsigned short*)alloc(DIM * DIM * 2);
    unsigned short* wt_lo2 = (unsigned short*)alloc(DIM * DIM * 2);
    unsigned short* wt_hi3 = (unsigned short*)alloc(DIM * DIM * 2);
    unsigned short* wt_lo3 = (unsigned short*)alloc(DIM * DIM * 2);
    float* part    = (float*)alloc((size_t)1024 * DIM * 4);  // pool partials
    // transient CSR-build arrays overlap bufA (bufA first written in layer-1 fused)
    int* cnt    = (int*)bufA;
    int* cursor = ((int*)bufA) + n;
    int* bsum   = ((int*)bufA) + 2 * n;
    int* bbase  = ((int*)bufA) + 2 * n + 256;

    // ---- CSR build (once; edge_index is layer-invariant) ----
    hipMemsetAsync(cnt, 0, (size_t)n * 4, stream);
    k_count<<<(e + 255) / 256, 256, 0, stream>>>(ecol, cnt, e);
    k_make_dis<<<(n + 255) / 256, 256, 0, stream>>>(cnt, dis, n);
    k_bsum<<<nb, 256, 0, stream>>>(cnt, bsum, n);
    k_bscan<<<1, 256, 0, stream>>>(bsum, bbase, nb);
    k_bfinal<<<nb, 256, 0, stream>>>(cnt, bbase, rowptr, cursor, n, e);
    k_fill<<<(e + 255) / 256, 256, 0, stream>>>(erow, ecol, cursor, csr_src, e);

    // ---- weight prep (transposed bf16 hi/lo) ----
    k_wprep<<<64, 256, 0, stream>>>(W1, wt_hi1, wt_lo1);
    k_wprep<<<64, 256, 0, stream>>>(W2, wt_hi2, wt_lo2);
    k_wprep<<<64, 256, 0, stream>>>(W3, wt_hi3, wt_lo3);

    dim3 fusedGrid((n + 63) / 64);

    k_gcn_fused<<<fusedGrid, 256, 0, stream>>>(x,    csr_src, rowptr, dis, wt_hi1, wt_lo1, b1, bufA, n);
    k_gcn_fused<<<fusedGrid, 256, 0, stream>>>(bufA, csr_src, rowptr, dis, wt_hi2, wt_lo2, b2, bufB, n);
    k_gcn_fused<<<fusedGrid, 256, 0, stream>>>(bufB, csr_src, rowptr, dis, wt_hi3, wt_lo3, b3, bufA, n);

    // global mean pool (two-phase, batch sorted -> binary-searched ranges)
    k_pool_part<<<1024, 256, 0, stream>>>(bufA, batch, part, n);
    k_pool_fin<<<N_GRAPHS, 128, 0, stream>>>(part, batch, (float*)d_out, n);
}

// Round 7
// 427.237 us; speedup vs baseline: 1.3870x; 1.3870x over previous
//
#include <hip/hip_runtime.h>

#define DIM 128
#define N_GRAPHS 64

typedef __attribute__((ext_vector_type(4))) float f32x4;
typedef __attribute__((ext_vector_type(8))) short s16x8;

// ---------------- degree / CSR precompute ----------------

__global__ void k_count(const int* __restrict__ col, int* __restrict__ cnt, int e) {
    int i = blockIdx.x * blockDim.x + threadIdx.x;
    if (i < e) atomicAdd(&cnt[col[i]], 1);
}

__global__ void k_make_dis(const int* __restrict__ cnt, float* __restrict__ dis, int n) {
    int i = blockIdx.x * blockDim.x + threadIdx.x;
    if (i < n) dis[i] = rsqrtf(1.0f + (float)cnt[i]);
}

__global__ __launch_bounds__(256) void k_bsum(const int* __restrict__ cnt,
                                              int* __restrict__ bsum, int n) {
    __shared__ int s[256];
    int t = threadIdx.x;
    int i = blockIdx.x * 256 + t;
    s[t] = (i < n) ? cnt[i] : 0;
    __syncthreads();
    for (int o = 128; o > 0; o >>= 1) {
        if (t < o) s[t] += s[t + o];
        __syncthreads();
    }
    if (t == 0) bsum[blockIdx.x] = s[0];
}

__global__ __launch_bounds__(256) void k_bscan(const int* __restrict__ bsum,
                                               int* __restrict__ bbase, int nb) {
    __shared__ int s[256];
    int t = threadIdx.x;
    int v = (t < nb) ? bsum[t] : 0;
    s[t] = v;
    __syncthreads();
    for (int o = 1; o < 256; o <<= 1) {
        int u = (t >= o) ? s[t - o] : 0;
        __syncthreads();
        s[t] += u;
        __syncthreads();
    }
    if (t < nb) bbase[t] = s[t] - v;  // exclusive
}

__global__ __launch_bounds__(256) void k_bfinal(const int* __restrict__ cnt,
        const int* __restrict__ bbase, int* __restrict__ rowptr,
        int* __restrict__ cursor, int n, int e) {
    __shared__ int s[256];
    int t = threadIdx.x;
    int i = blockIdx.x * 256 + t;
    int v = (i < n) ? cnt[i] : 0;
    s[t] = v;
    __syncthreads();
    for (int o = 1; o < 256; o <<= 1) {
        int u = (t >= o) ? s[t - o] : 0;
        __syncthreads();
        s[t] += u;
        __syncthreads();
    }
    if (i < n) {
        int excl = s[t] - v + bbase[blockIdx.x];
        rowptr[i] = excl;
        cursor[i] = excl;
        if (i == n - 1) rowptr[n] = e;
    }
}

__global__ void k_fill(const int* __restrict__ row, const int* __restrict__ col,
                       int* __restrict__ cursor, int* __restrict__ csr_src, int e) {
    int i = blockIdx.x * blockDim.x + threadIdx.x;
    if (i >= e) return;
    int pos = atomicAdd(&cursor[col[i]], 1);
    csr_src[pos] = row[i];
}

// ---------------- aggregation: gather form, no atomics ----------------
// one wave per target node; lane l owns columns [2l, 2l+1]; edge loop unrolled x4

__global__ __launch_bounds__(256) void k_gcn_agg(const float* __restrict__ in,
        const int* __restrict__ csr_src, const int* __restrict__ rowptr,
        const float* __restrict__ dis, float* __restrict__ agg, int n) {
    int wid = (blockIdx.x * blockDim.x + threadIdx.x) >> 6;
    if (wid >= n) return;
    int lane = threadIdx.x & 63;
    const int coff = lane * 2;
    float d = dis[wid];
    float2 acc = *(const float2*)&in[(size_t)wid * DIM + coff];
    float dd = d * d;  // self-loop weight
    acc.x *= dd; acc.y *= dd;
    int p = rowptr[wid], p1 = rowptr[wid + 1];
    for (; p + 3 < p1; p += 4) {
        int s0 = csr_src[p], s1 = csr_src[p + 1], s2 = csr_src[p + 2], s3 = csr_src[p + 3];
        float w0 = d * dis[s0], w1 = d * dis[s1], w2 = d * dis[s2], w3 = d * dis[s3];
        float2 v0 = *(const float2*)&in[(size_t)s0 * DIM + coff];
        float2 v1 = *(const float2*)&in[(size_t)s1 * DIM + coff];
        float2 v2 = *(const float2*)&in[(size_t)s2 * DIM + coff];
        float2 v3 = *(const float2*)&in[(size_t)s3 * DIM + coff];
        acc.x += v0.x * w0; acc.y += v0.y * w0;
        acc.x += v1.x * w1; acc.y += v1.y * w1;
        acc.x += v2.x * w2; acc.y += v2.y * w2;
        acc.x += v3.x * w3; acc.y += v3.y * w3;
    }
    for (; p < p1; p++) {
        int s = csr_src[p];
        float w = d * dis[s];
        float2 v = *(const float2*)&in[(size_t)s * DIM + coff];
        acc.x += v.x * w;
        acc.y += v.y * w;
    }
    *(float2*)&agg[(size_t)wid * DIM + coff] = acc;
}

// ---------------- bf16 helpers ----------------

__device__ __forceinline__ unsigned short bf16_rtne(float f) {
    unsigned u = __builtin_bit_cast(unsigned, f);
    unsigned r = u + 0x7FFFu + ((u >> 16) & 1u);
    return (unsigned short)(r >> 16);
}
__device__ __forceinline__ float bf16_to_f32(unsigned short h) {
    unsigned u = ((unsigned)h) << 16;
    return __builtin_bit_cast(float, u);
}

// W[k][c] (128x128 f32) -> Wt_hi[c][k], Wt_lo[c][k] (bf16 split)
__global__ __launch_bounds__(256) void k_wprep(const float* __restrict__ W,
        unsigned short* __restrict__ wt_hi, unsigned short* __restrict__ wt_lo) {
    int i = blockIdx.x * 256 + threadIdx.x;  // 16384 total
    int k = i >> 7, c = i & 127;
    float w = W[i];
    unsigned short h = bf16_rtne(w);
    unsigned short l = bf16_rtne(w - bf16_to_f32(h));
    wt_hi[c * DIM + k] = h;
    wt_lo[c * DIM + k] = l;
}

// ---------------- MFMA matmul + bias + relu ----------------
// out[r][:] = relu(A[r][:] @ W + b); 3-term bf16 split A@W ~= Ah@Wh + Al@Wh + Ah@Wl
// mfma_f32_16x16x32_bf16: A row=lane&15, k=(lane>>4)*8+j ; C col=lane&15, row=(lane>>4)*4+reg

__global__ __launch_bounds__(256) void k_mm_mfma(
        const float* __restrict__ A, const unsigned short* __restrict__ wt_hi,
        const unsigned short* __restrict__ wt_lo, const float* __restrict__ bias,
        float* __restrict__ out, int n) {
    int tid = threadIdx.x;
    int wave = tid >> 6, lane = tid & 63;
    int r0 = blockIdx.x * 64 + wave * 16;
    int lrow = lane & 15;          // A-frag row / C col index
    int lk = lane >> 4;            // k-group 0..3
    int row = r0 + lrow;
    int rowc = row < n ? row : (n - 1);

    const float* ar = A + (size_t)rowc * DIM;
    s16x8 ah[4], al[4];
#pragma unroll
    for (int ks = 0; ks < 4; ks++) {
        int kb = ks * 32 + lk * 8;
        float4 u0 = *(const float4*)&ar[kb];
        float4 u1 = *(const float4*)&ar[kb + 4];
        float v[8] = {u0.x, u0.y, u0.z, u0.w, u1.x, u1.y, u1.z, u1.w};
        s16x8 h, l;
#pragma unroll
        for (int j = 0; j < 8; j++) {
            unsigned short hb = bf16_rtne(v[j]);
            h[j] = (short)hb;
            l[j] = (short)bf16_rtne(v[j] - bf16_to_f32(hb));
        }
        ah[ks] = h; al[ks] = l;
    }

    f32x4 acc[8];
#pragma unroll
    for (int ct = 0; ct < 8; ct++) {
        const unsigned short* bh_base = wt_hi + (size_t)(ct * 16 + lrow) * DIM + lk * 8;
        const unsigned short* bl_base = wt_lo + (size_t)(ct * 16 + lrow) * DIM + lk * 8;
        s16x8 bh[4], bl[4];
#pragma unroll
        for (int ks = 0; ks < 4; ks++) {
            bh[ks] = *(const s16x8*)(bh_base + ks * 32);
            bl[ks] = *(const s16x8*)(bl_base + ks * 32);
        }
        f32x4 c = {0.f, 0.f, 0.f, 0.f};
#pragma unroll
        for (int ks = 0; ks < 4; ks++) {
            c = __builtin_amdgcn_mfma_f32_16x16x32_bf16(ah[ks], bh[ks], c, 0, 0, 0);
            c = __builtin_amdgcn_mfma_f32_16x16x32_bf16(al[ks], bh[ks], c, 0, 0, 0);
            c = __builtin_amdgcn_mfma_f32_16x16x32_bf16(ah[ks], bl[ks], c, 0, 0, 0);
        }
        acc[ct] = c;
    }

#pragma unroll
    for (int ct = 0; ct < 8; ct++) {
        int col = ct * 16 + lrow;
        float bcol = bias[col];
#pragma unroll
        for (int reg = 0; reg < 4; reg++) {
            int orow = r0 + lk * 4 + reg;
            if (orow < n) {
                float v = acc[ct][reg] + bcol;
                out[(size_t)orow * DIM + col] = v > 0.f ? v : 0.f;
            }
        }
    }
}

// ---------------- global mean pool: two-phase, device-filling ----------------
// phase A: 16 slices x 64 graphs = 1024 blocks -> partial sums
__global__ __launch_bounds__(256) void k_pool_part(const float* __restrict__ h,
        const int* __restrict__ batch, float* __restrict__ part, int n) {
    int g = blockIdx.x >> 4, s = blockIdx.x & 15;
    int lo = 0, hi = n;
    while (lo < hi) { int m = (lo + hi) >> 1; if (batch[m] < g) lo = m + 1; else hi = m; }
    int start = lo;
    int lo2 = start, hi2 = n;
    while (lo2 < hi2) { int m = (lo2 + hi2) >> 1; if (batch[m] < g + 1) lo2 = m + 1; else hi2 = m; }
    int end = lo2;

    int t = threadIdx.x;
    int wave = t >> 6, lane = t & 63;
    float2 acc = {0.f, 0.f};
    for (int r = start + s + 16 * wave; r < end; r += 64) {
        float2 v = *(const float2*)&h[(size_t)r * DIM + lane * 2];
        acc.x += v.x; acc.y += v.y;
    }
    __shared__ float2 red[4][64];
    red[wave][lane] = acc;
    __syncthreads();
    if (t < 64) {
        float2 s0 = red[0][t], s1 = red[1][t], s2 = red[2][t], s3 = red[3][t];
        float2 o;
        o.x = s0.x + s1.x + s2.x + s3.x;
        o.y = s0.y + s1.y + s2.y + s3.y;
        *(float2*)&part[(size_t)blockIdx.x * DIM + t * 2] = o;
    }
}

// phase B: 64 blocks x 128 threads: combine 16 partials, divide by count
__global__ __launch_bounds__(128) void k_pool_fin(const float* __restrict__ part,
        const int* __restrict__ batch, float* __restrict__ out, int n) {
    int g = blockIdx.x, c = threadIdx.x;
    int lo = 0, hi = n;
    while (lo < hi) { int m = (lo + hi) >> 1; if (batch[m] < g) lo = m + 1; else hi = m; }
    int start = lo;
    int lo2 = start, hi2 = n;
    while (lo2 < hi2) { int m = (lo2 + hi2) >> 1; if (batch[m] < g + 1) lo2 = m + 1; else hi2 = m; }
    int end = lo2;

    float s = 0.f;
#pragma unroll
    for (int k = 0; k < 16; k++) s += part[(size_t)(g * 16 + k) * DIM + c];
    float cnt = (float)(end - start);
    cnt = cnt > 1.f ? cnt : 1.f;
    out[g * DIM + c] = s / cnt;
}

// ---------------- launch ----------------

extern "C" void kernel_launch(void* const* d_in, const int* in_sizes, int n_in,
                              void* d_out, int out_size, void* d_ws, size_t ws_size,
                              hipStream_t stream) {
    const float* x  = (const float*)d_in[0];
    const int*   ei = (const int*)d_in[1];
    const int*   batch = (const int*)d_in[2];
    const float* W1 = (const float*)d_in[3];
    const float* b1 = (const float*)d_in[4];
    const float* W2 = (const float*)d_in[5];
    const float* b2 = (const float*)d_in[6];
    const float* W3 = (const float*)d_in[7];
    const float* b3 = (const float*)d_in[8];

    int n = in_sizes[0] / DIM;  // 50000
    int e = in_sizes[1] / 2;    // 800000
    const int* erow = ei;       // sources
    const int* ecol = ei + e;   // targets
    int nb = (n + 255) / 256;   // 196 scan blocks (<=256 required)

    char* ws = (char*)d_ws;
    size_t off = 0;
    auto alloc = [&](size_t bytes) -> void* {
        void* p = (void*)(ws + off);
        off += (bytes + 255) & ~(size_t)255;
        return p;
    };
    float* dis     = (float*)alloc((size_t)n * 4);
    int*   rowptr  = (int*)alloc((size_t)(n + 1) * 4);
    int*   csr_src = (int*)alloc((size_t)e * 4);
    float* agg     = (float*)alloc((size_t)n * DIM * 4);
    float* bufA    = (float*)alloc((size_t)n * DIM * 4);
    float* bufB    = (float*)alloc((size_t)n * DIM * 4);
    unsigned short* wt_hi1 = (unsigned short*)alloc(DIM * DIM * 2);
    unsigned short* wt_lo1 = (unsigned short*)alloc(DIM * DIM * 2);
    unsigned short* wt_hi2 = (unsigned short*)alloc(DIM * DIM * 2);
    unsigned short* wt_lo2 = (unsigned short*)alloc(DIM * DIM * 2);
    unsigned short* wt_hi3 = (unsigned short*)alloc(DIM * DIM * 2);
    unsigned short* wt_lo3 = (unsigned short*)alloc(DIM * DIM * 2);
    float* part    = (float*)alloc((size_t)1024 * DIM * 4);  // pool partials
    // transient CSR-build arrays overlap bufA (bufA first written in layer-1 mm)
    int* cnt    = (int*)bufA;
    int* cursor = ((int*)bufA) + n;
    int* bsum   = ((int*)bufA) + 2 * n;
    int* bbase  = ((int*)bufA) + 2 * n + 256;

    // ---- CSR build (once; edge_index is layer-invariant) ----
    hipMemsetAsync(cnt, 0, (size_t)n * 4, stream);
    k_count<<<(e + 255) / 256, 256, 0, stream>>>(ecol, cnt, e);
    k_make_dis<<<(n + 255) / 256, 256, 0, stream>>>(cnt, dis, n);
    k_bsum<<<nb, 256, 0, stream>>>(cnt, bsum, n);
    k_bscan<<<1, 256, 0, stream>>>(bsum, bbase, nb);
    k_bfinal<<<nb, 256, 0, stream>>>(cnt, bbase, rowptr, cursor, n, e);
    k_fill<<<(e + 255) / 256, 256, 0, stream>>>(erow, ecol, cursor, csr_src, e);

    // ---- weight prep (transposed bf16 hi/lo) ----
    k_wprep<<<64, 256, 0, stream>>>(W1, wt_hi1, wt_lo1);
    k_wprep<<<64, 256, 0, stream>>>(W2, wt_hi2, wt_lo2);
    k_wprep<<<64, 256, 0, stream>>>(W3, wt_hi3, wt_lo3);

    dim3 aggGrid(((size_t)n * 64 + 255) / 256);
    dim3 mmGrid((n + 63) / 64);

    // layer 1
    k_gcn_agg<<<aggGrid, 256, 0, stream>>>(x, csr_src, rowptr, dis, agg, n);
    k_mm_mfma<<<mmGrid, 256, 0, stream>>>(agg, wt_hi1, wt_lo1, b1, bufA, n);
    // layer 2
    k_gcn_agg<<<aggGrid, 256, 0, stream>>>(bufA, csr_src, rowptr, dis, agg, n);
    k_mm_mfma<<<mmGrid, 256, 0, stream>>>(agg, wt_hi2, wt_lo2, b2, bufB, n);
    // layer 3
    k_gcn_agg<<<aggGrid, 256, 0, stream>>>(bufB, csr_src, rowptr, dis, agg, n);
    k_mm_mfma<<<mmGrid, 256, 0, stream>>>(agg, wt_hi3, wt_lo3, b3, bufA, n);

    // global mean pool (two-phase, batch sorted -> binary-searched ranges)
    k_pool_part<<<1024, 256, 0, stream>>>(bufA, batch, part, n);
    k_pool_fin<<<N_GRAPHS, 128, 0, stream>>>(part, batch, (float*)d_out, n);
}

// Round 8
// 410.309 us; speedup vs baseline: 1.4442x; 1.0413x over previous
//
#include <hip/hip_runtime.h>
#include <hip/hip_bf16.h>

#define DIM 128
#define N_GRAPHS 64

typedef __attribute__((ext_vector_type(4))) float f32x4;
typedef __attribute__((ext_vector_type(8))) short s16x8;

// ---------------- degree / CSR precompute ----------------

__global__ void k_count4(const int4* __restrict__ col4, int* __restrict__ cnt, int e4) {
    int i = blockIdx.x * blockDim.x + threadIdx.x;
    if (i < e4) {
        int4 c = col4[i];
        atomicAdd(&cnt[c.x], 1);
        atomicAdd(&cnt[c.y], 1);
        atomicAdd(&cnt[c.z], 1);
        atomicAdd(&cnt[c.w], 1);
    }
}

__global__ __launch_bounds__(256) void k_bsum(const int* __restrict__ cnt,
                                              int* __restrict__ bsum, int n) {
    __shared__ int s[256];
    int t = threadIdx.x;
    int i = blockIdx.x * 256 + t;
    s[t] = (i < n) ? cnt[i] : 0;
    __syncthreads();
    for (int o = 128; o > 0; o >>= 1) {
        if (t < o) s[t] += s[t + o];
        __syncthreads();
    }
    if (t == 0) bsum[blockIdx.x] = s[0];
}

__global__ __launch_bounds__(256) void k_bscan(const int* __restrict__ bsum,
                                               int* __restrict__ bbase, int nb) {
    __shared__ int s[256];
    int t = threadIdx.x;
    int v = (t < nb) ? bsum[t] : 0;
    s[t] = v;
    __syncthreads();
    for (int o = 1; o < 256; o <<= 1) {
        int u = (t >= o) ? s[t - o] : 0;
        __syncthreads();
        s[t] += u;
        __syncthreads();
    }
    if (t < nb) bbase[t] = s[t] - v;  // exclusive
}

// also emits dis[i] = rsqrt(1 + degree) (self loop included)
__global__ __launch_bounds__(256) void k_bfinal(const int* __restrict__ cnt,
        const int* __restrict__ bbase, int* __restrict__ rowptr,
        int* __restrict__ cursor, float* __restrict__ dis, int n, int e) {
    __shared__ int s[256];
    int t = threadIdx.x;
    int i = blockIdx.x * 256 + t;
    int v = (i < n) ? cnt[i] : 0;
    s[t] = v;
    __syncthreads();
    for (int o = 1; o < 256; o <<= 1) {
        int u = (t >= o) ? s[t - o] : 0;
        __syncthreads();
        s[t] += u;
        __syncthreads();
    }
    if (i < n) {
        int excl = s[t] - v + bbase[blockIdx.x];
        rowptr[i] = excl;
        cursor[i] = excl;
        dis[i] = rsqrtf(1.0f + (float)v);
        if (i == n - 1) rowptr[n] = e;
    }
}

__global__ void k_fill4(const int4* __restrict__ row4, const int4* __restrict__ col4,
                        int* __restrict__ cursor, int* __restrict__ csr_src, int e4) {
    int i = blockIdx.x * blockDim.x + threadIdx.x;
    if (i >= e4) return;
    int4 r = row4[i];
    int4 c = col4[i];
    csr_src[atomicAdd(&cursor[c.x], 1)] = r.x;
    csr_src[atomicAdd(&cursor[c.y], 1)] = r.y;
    csr_src[atomicAdd(&cursor[c.z], 1)] = r.z;
    csr_src[atomicAdd(&cursor[c.w], 1)] = r.w;
}

// ---------------- aggregation: gather form, no atomics ----------------

__global__ __launch_bounds__(256) void k_gcn_agg(const float* __restrict__ in,
        const int* __restrict__ csr_src, const int* __restrict__ rowptr,
        const float* __restrict__ dis, float* __restrict__ agg, int n) {
    int wid = (blockIdx.x * blockDim.x + threadIdx.x) >> 6;
    if (wid >= n) return;
    int lane = threadIdx.x & 63;
    const int coff = lane * 2;
    float d = dis[wid];
    float2 acc = *(const float2*)&in[(size_t)wid * DIM + coff];
    float dd = d * d;  // self-loop weight
    acc.x *= dd; acc.y *= dd;
    int p = rowptr[wid], p1 = rowptr[wid + 1];
    for (; p + 3 < p1; p += 4) {
        int s0 = csr_src[p], s1 = csr_src[p + 1], s2 = csr_src[p + 2], s3 = csr_src[p + 3];
        float w0 = d * dis[s0], w1 = d * dis[s1], w2 = d * dis[s2], w3 = d * dis[s3];
        float2 v0 = *(const float2*)&in[(size_t)s0 * DIM + coff];
        float2 v1 = *(const float2*)&in[(size_t)s1 * DIM + coff];
        float2 v2 = *(const float2*)&in[(size_t)s2 * DIM + coff];
        float2 v3 = *(const float2*)&in[(size_t)s3 * DIM + coff];
        acc.x += v0.x * w0; acc.y += v0.y * w0;
        acc.x += v1.x * w1; acc.y += v1.y * w1;
        acc.x += v2.x * w2; acc.y += v2.y * w2;
        acc.x += v3.x * w3; acc.y += v3.y * w3;
    }
    for (; p < p1; p++) {
        int s = csr_src[p];
        float w = d * dis[s];
        float2 v = *(const float2*)&in[(size_t)s * DIM + coff];
        acc.x += v.x * w;
        acc.y += v.y * w;
    }
    *(float2*)&agg[(size_t)wid * DIM + coff] = acc;
}

// ---------------- bf16 helpers (hardware cvt) ----------------

__device__ __forceinline__ short bf16h(float f) {
    return __builtin_bit_cast(short, __float2bfloat16(f));  // HW RTNE cvt
}
__device__ __forceinline__ float bf16f(short h) {
    return __bfloat162float(__builtin_bit_cast(__hip_bfloat16, h));
}

// W[k][c] (128x128 f32) x3 -> Wt_hi[c][k], Wt_lo[c][k] (bf16 split); 3 weights fused
__global__ __launch_bounds__(256) void k_wprep3(
        const float* __restrict__ W1, const float* __restrict__ W2,
        const float* __restrict__ W3,
        unsigned short* __restrict__ hi1, unsigned short* __restrict__ lo1,
        unsigned short* __restrict__ hi2, unsigned short* __restrict__ lo2,
        unsigned short* __restrict__ hi3, unsigned short* __restrict__ lo3) {
    int m = blockIdx.x >> 6;               // 64 blocks per matrix
    int i = (blockIdx.x & 63) * 256 + threadIdx.x;  // 16384 per matrix
    const float* W = (m == 0) ? W1 : (m == 1) ? W2 : W3;
    unsigned short* hi = (m == 0) ? hi1 : (m == 1) ? hi2 : hi3;
    unsigned short* lo = (m == 0) ? lo1 : (m == 1) ? lo2 : lo3;
    int k = i >> 7, c = i & 127;
    float w = W[i];
    short h = bf16h(w);
    short l = bf16h(w - bf16f(h));
    hi[c * DIM + k] = (unsigned short)h;
    lo[c * DIM + k] = (unsigned short)l;
}

// ---------------- MFMA matmul + bias + relu ----------------
// out[r][:] = relu(A[r][:] @ W + b); 3-term bf16 split A@W ~= Ah@Wh + Al@Wh + Ah@Wl
// mfma_f32_16x16x32_bf16: A row=lane&15, k=(lane>>4)*8+j ; C col=lane&15, row=(lane>>4)*4+reg

__global__ __launch_bounds__(256) void k_mm_mfma(
        const float* __restrict__ A, const unsigned short* __restrict__ wt_hi,
        const unsigned short* __restrict__ wt_lo, const float* __restrict__ bias,
        float* __restrict__ out, int n) {
    int tid = threadIdx.x;
    int wave = tid >> 6, lane = tid & 63;
    int r0 = blockIdx.x * 64 + wave * 16;
    int lrow = lane & 15;          // A-frag row / C col index
    int lk = lane >> 4;            // k-group 0..3
    bool full = (blockIdx.x * 64 + 64 <= n);
    int row = r0 + lrow;
    int rowc = row < n ? row : (n - 1);

    const float* ar = A + (size_t)rowc * DIM;
    s16x8 ah[4], al[4];
#pragma unroll
    for (int ks = 0; ks < 4; ks++) {
        int kb = ks * 32 + lk * 8;
        float4 u0 = *(const float4*)&ar[kb];
        float4 u1 = *(const float4*)&ar[kb + 4];
        float v[8] = {u0.x, u0.y, u0.z, u0.w, u1.x, u1.y, u1.z, u1.w};
        s16x8 h, l;
#pragma unroll
        for (int j = 0; j < 8; j++) {
            short hb = bf16h(v[j]);
            h[j] = hb;
            l[j] = bf16h(v[j] - bf16f(hb));
        }
        ah[ks] = h; al[ks] = l;
    }

    f32x4 acc[8];
#pragma unroll
    for (int ct = 0; ct < 8; ct++) {
        const unsigned short* bh_base = wt_hi + (size_t)(ct * 16 + lrow) * DIM + lk * 8;
        const unsigned short* bl_base = wt_lo + (size_t)(ct * 16 + lrow) * DIM + lk * 8;
        s16x8 bh[4], bl[4];
#pragma unroll
        for (int ks = 0; ks < 4; ks++) {
            bh[ks] = *(const s16x8*)(bh_base + ks * 32);
            bl[ks] = *(const s16x8*)(bl_base + ks * 32);
        }
        f32x4 c = {0.f, 0.f, 0.f, 0.f};
#pragma unroll
        for (int ks = 0; ks < 4; ks++) {
            c = __builtin_amdgcn_mfma_f32_16x16x32_bf16(ah[ks], bh[ks], c, 0, 0, 0);
            c = __builtin_amdgcn_mfma_f32_16x16x32_bf16(al[ks], bh[ks], c, 0, 0, 0);
            c = __builtin_amdgcn_mfma_f32_16x16x32_bf16(ah[ks], bl[ks], c, 0, 0, 0);
        }
        acc[ct] = c;
    }

    if (full) {
#pragma unroll
        for (int ct = 0; ct < 8; ct++) {
            int col = ct * 16 + lrow;
            float bcol = bias[col];
#pragma unroll
            for (int reg = 0; reg < 4; reg++) {
                int orow = r0 + lk * 4 + reg;
                float v = acc[ct][reg] + bcol;
                out[(size_t)orow * DIM + col] = v > 0.f ? v : 0.f;
            }
        }
    } else {
#pragma unroll
        for (int ct = 0; ct < 8; ct++) {
            int col = ct * 16 + lrow;
            float bcol = bias[col];
#pragma unroll
            for (int reg = 0; reg < 4; reg++) {
                int orow = r0 + lk * 4 + reg;
                if (orow < n) {
                    float v = acc[ct][reg] + bcol;
                    out[(size_t)orow * DIM + col] = v > 0.f ? v : 0.f;
                }
            }
        }
    }
}

// ---------------- global mean pool: two-phase, device-filling ----------------

__global__ __launch_bounds__(256) void k_pool_part(const float* __restrict__ h,
        const int* __restrict__ batch, float* __restrict__ part, int n) {
    int g = blockIdx.x >> 4, s = blockIdx.x & 15;
    int lo = 0, hi = n;
    while (lo < hi) { int m = (lo + hi) >> 1; if (batch[m] < g) lo = m + 1; else hi = m; }
    int start = lo;
    int lo2 = start, hi2 = n;
    while (lo2 < hi2) { int m = (lo2 + hi2) >> 1; if (batch[m] < g + 1) lo2 = m + 1; else hi2 = m; }
    int end = lo2;

    int t = threadIdx.x;
    int wave = t >> 6, lane = t & 63;
    float2 acc = {0.f, 0.f};
    for (int r = start + s + 16 * wave; r < end; r += 64) {
        float2 v = *(const float2*)&h[(size_t)r * DIM + lane * 2];
        acc.x += v.x; acc.y += v.y;
    }
    __shared__ float2 red[4][64];
    red[wave][lane] = acc;
    __syncthreads();
    if (t < 64) {
        float2 s0 = red[0][t], s1 = red[1][t], s2 = red[2][t], s3 = red[3][t];
        float2 o;
        o.x = s0.x + s1.x + s2.x + s3.x;
        o.y = s0.y + s1.y + s2.y + s3.y;
        *(float2*)&part[(size_t)blockIdx.x * DIM + t * 2] = o;
    }
}

__global__ __launch_bounds__(128) void k_pool_fin(const float* __restrict__ part,
        const int* __restrict__ batch, float* __restrict__ out, int n) {
    int g = blockIdx.x, c = threadIdx.x;
    int lo = 0, hi = n;
    while (lo < hi) { int m = (lo + hi) >> 1; if (batch[m] < g) lo = m + 1; else hi = m; }
    int start = lo;
    int lo2 = start, hi2 = n;
    while (lo2 < hi2) { int m = (lo2 + hi2) >> 1; if (batch[m] < g + 1) lo2 = m + 1; else hi2 = m; }
    int end = lo2;

    float s = 0.f;
#pragma unroll
    for (int k = 0; k < 16; k++) s += part[(size_t)(g * 16 + k) * DIM + c];
    float cnt = (float)(end - start);
    cnt = cnt > 1.f ? cnt : 1.f;
    out[g * DIM + c] = s / cnt;
}

// ---------------- launch ----------------

extern "C" void kernel_launch(void* const* d_in, const int* in_sizes, int n_in,
                              void* d_out, int out_size, void* d_ws, size_t ws_size,
                              hipStream_t stream) {
    const float* x  = (const float*)d_in[0];
    const int*   ei = (const int*)d_in[1];
    const int*   batch = (const int*)d_in[2];
    const float* W1 = (const float*)d_in[3];
    const float* b1 = (const float*)d_in[4];
    const float* W2 = (const float*)d_in[5];
    const float* b2 = (const float*)d_in[6];
    const float* W3 = (const float*)d_in[7];
    const float* b3 = (const float*)d_in[8];

    int n = in_sizes[0] / DIM;  // 50000
    int e = in_sizes[1] / 2;    // 800000
    const int* erow = ei;       // sources
    const int* ecol = ei + e;   // targets
    int e4 = e / 4;             // 200000 (e divisible by 4)
    int nb = (n + 255) / 256;   // 196 scan blocks (<=256 required)

    char* ws = (char*)d_ws;
    size_t off = 0;
    auto alloc = [&](size_t bytes) -> void* {
        void* p = (void*)(ws + off);
        off += (bytes + 255) & ~(size_t)255;
        return p;
    };
    float* dis     = (float*)alloc((size_t)n * 4);
    int*   rowptr  = (int*)alloc((size_t)(n + 1) * 4);
    int*   csr_src = (int*)alloc((size_t)e * 4);
    float* agg     = (float*)alloc((size_t)n * DIM * 4);
    float* bufA    = (float*)alloc((size_t)n * DIM * 4);
    float* bufB    = (float*)alloc((size_t)n * DIM * 4);
    unsigned short* wt_hi1 = (unsigned short*)alloc(DIM * DIM * 2);
    unsigned short* wt_lo1 = (unsigned short*)alloc(DIM * DIM * 2);
    unsigned short* wt_hi2 = (unsigned short*)alloc(DIM * DIM * 2);
    unsigned short* wt_lo2 = (unsigned short*)alloc(DIM * DIM * 2);
    unsigned short* wt_hi3 = (unsigned short*)alloc(DIM * DIM * 2);
    unsigned short* wt_lo3 = (unsigned short*)alloc(DIM * DIM * 2);
    float* part    = (float*)alloc((size_t)1024 * DIM * 4);  // pool partials
    // transient CSR-build arrays overlap bufA (bufA first written in layer-1 mm)
    int* cnt    = (int*)bufA;
    int* cursor = ((int*)bufA) + n;
    int* bsum   = ((int*)bufA) + 2 * n;
    int* bbase  = ((int*)bufA) + 2 * n + 256;

    // ---- CSR build (once; edge_index is layer-invariant) ----
    hipMemsetAsync(cnt, 0, (size_t)n * 4, stream);
    k_count4<<<(e4 + 255) / 256, 256, 0, stream>>>((const int4*)ecol, cnt, e4);
    k_bsum<<<nb, 256, 0, stream>>>(cnt, bsum, n);
    k_bscan<<<1, 256, 0, stream>>>(bsum, bbase, nb);
    k_bfinal<<<nb, 256, 0, stream>>>(cnt, bbase, rowptr, cursor, dis, n, e);
    k_fill4<<<(e4 + 255) / 256, 256, 0, stream>>>((const int4*)erow, (const int4*)ecol,
                                                  cursor, csr_src, e4);

    // ---- weight prep (transposed bf16 hi/lo, all 3 fused) ----
    k_wprep3<<<192, 256, 0, stream>>>(W1, W2, W3, wt_hi1, wt_lo1, wt_hi2, wt_lo2,
                                      wt_hi3, wt_lo3);

    dim3 aggGrid(((size_t)n * 64 + 255) / 256);
    dim3 mmGrid((n + 63) / 64);

    // layer 1
    k_gcn_agg<<<aggGrid, 256, 0, stream>>>(x, csr_src, rowptr, dis, agg, n);
    k_mm_mfma<<<mmGrid, 256, 0, stream>>>(agg, wt_hi1, wt_lo1, b1, bufA, n);
    // layer 2
    k_gcn_agg<<<aggGrid, 256, 0, stream>>>(bufA, csr_src, rowptr, dis, agg, n);
    k_mm_mfma<<<mmGrid, 256, 0, stream>>>(agg, wt_hi2, wt_lo2, b2, bufB, n);
    // layer 3
    k_gcn_agg<<<aggGrid, 256, 0, stream>>>(bufB, csr_src, rowptr, dis, agg, n);
    k_mm_mfma<<<mmGrid, 256, 0, stream>>>(agg, wt_hi3, wt_lo3, b3, bufA, n);

    // global mean pool (two-phase, batch sorted -> binary-searched ranges)
    k_pool_part<<<1024, 256, 0, stream>>>(bufA, batch, part, n);
    k_pool_fin<<<N_GRAPHS, 128, 0, stream>>>(part, batch, (float*)d_out, n);
}

// Round 9
// 358.621 us; speedup vs baseline: 1.6523x; 1.1441x over previous
//
#include <hip/hip_runtime.h>
#include <hip/hip_bf16.h>

#define DIM 128
#define N_GRAPHS 64
#define SSTR 136  // LDS row stride in shorts (272 B): 2-way bank aliasing only (free)

typedef __attribute__((ext_vector_type(4))) float f32x4;
typedef __attribute__((ext_vector_type(8))) short s16x8;

// ---------------- degree / CSR precompute ----------------

__global__ void k_count4(const int4* __restrict__ col4, int* __restrict__ cnt, int e4) {
    int i = blockIdx.x * blockDim.x + threadIdx.x;
    if (i < e4) {
        int4 c = col4[i];
        atomicAdd(&cnt[c.x], 1);
        atomicAdd(&cnt[c.y], 1);
        atomicAdd(&cnt[c.z], 1);
        atomicAdd(&cnt[c.w], 1);
    }
}

__global__ __launch_bounds__(256) void k_bsum(const int* __restrict__ cnt,
                                              int* __restrict__ bsum, int n) {
    __shared__ int s[256];
    int t = threadIdx.x;
    int i = blockIdx.x * 256 + t;
    s[t] = (i < n) ? cnt[i] : 0;
    __syncthreads();
    for (int o = 128; o > 0; o >>= 1) {
        if (t < o) s[t] += s[t + o];
        __syncthreads();
    }
    if (t == 0) bsum[blockIdx.x] = s[0];
}

__global__ __launch_bounds__(256) void k_bscan(const int* __restrict__ bsum,
                                               int* __restrict__ bbase, int nb) {
    __shared__ int s[256];
    int t = threadIdx.x;
    int v = (t < nb) ? bsum[t] : 0;
    s[t] = v;
    __syncthreads();
    for (int o = 1; o < 256; o <<= 1) {
        int u = (t >= o) ? s[t - o] : 0;
        __syncthreads();
        s[t] += u;
        __syncthreads();
    }
    if (t < nb) bbase[t] = s[t] - v;  // exclusive
}

// also emits dis[i] = rsqrt(1 + degree) (self loop included)
__global__ __launch_bounds__(256) void k_bfinal(const int* __restrict__ cnt,
        const int* __restrict__ bbase, int* __restrict__ rowptr,
        int* __restrict__ cursor, float* __restrict__ dis, int n, int e) {
    __shared__ int s[256];
    int t = threadIdx.x;
    int i = blockIdx.x * 256 + t;
    int v = (i < n) ? cnt[i] : 0;
    s[t] = v;
    __syncthreads();
    for (int o = 1; o < 256; o <<= 1) {
        int u = (t >= o) ? s[t - o] : 0;
        __syncthreads();
        s[t] += u;
        __syncthreads();
    }
    if (i < n) {
        int excl = s[t] - v + bbase[blockIdx.x];
        rowptr[i] = excl;
        cursor[i] = excl;
        dis[i] = rsqrtf(1.0f + (float)v);
        if (i == n - 1) rowptr[n] = e;
    }
}

__global__ void k_fill4(const int4* __restrict__ row4, const int4* __restrict__ col4,
                        int* __restrict__ cursor, int* __restrict__ csr_src, int e4) {
    int i = blockIdx.x * blockDim.x + threadIdx.x;
    if (i >= e4) return;
    int4 r = row4[i];
    int4 c = col4[i];
    csr_src[atomicAdd(&cursor[c.x], 1)] = r.x;
    csr_src[atomicAdd(&cursor[c.y], 1)] = r.y;
    csr_src[atomicAdd(&cursor[c.z], 1)] = r.z;
    csr_src[atomicAdd(&cursor[c.w], 1)] = r.w;
}

// ---------------- aggregation: gather form, no atomics ----------------

__global__ __launch_bounds__(256) void k_gcn_agg(const float* __restrict__ in,
        const int* __restrict__ csr_src, const int* __restrict__ rowptr,
        const float* __restrict__ dis, float* __restrict__ agg, int n) {
    int wid = (blockIdx.x * blockDim.x + threadIdx.x) >> 6;
    if (wid >= n) return;
    int lane = threadIdx.x & 63;
    const int coff = lane * 2;
    float d = dis[wid];
    float2 acc = *(const float2*)&in[(size_t)wid * DIM + coff];
    float dd = d * d;  // self-loop weight
    acc.x *= dd; acc.y *= dd;
    int p = rowptr[wid], p1 = rowptr[wid + 1];
    for (; p + 3 < p1; p += 4) {
        int s0 = csr_src[p], s1 = csr_src[p + 1], s2 = csr_src[p + 2], s3 = csr_src[p + 3];
        float w0 = d * dis[s0], w1 = d * dis[s1], w2 = d * dis[s2], w3 = d * dis[s3];
        float2 v0 = *(const float2*)&in[(size_t)s0 * DIM + coff];
        float2 v1 = *(const float2*)&in[(size_t)s1 * DIM + coff];
        float2 v2 = *(const float2*)&in[(size_t)s2 * DIM + coff];
        float2 v3 = *(const float2*)&in[(size_t)s3 * DIM + coff];
        acc.x += v0.x * w0; acc.y += v0.y * w0;
        acc.x += v1.x * w1; acc.y += v1.y * w1;
        acc.x += v2.x * w2; acc.y += v2.y * w2;
        acc.x += v3.x * w3; acc.y += v3.y * w3;
    }
    for (; p < p1; p++) {
        int s = csr_src[p];
        float w = d * dis[s];
        float2 v = *(const float2*)&in[(size_t)s * DIM + coff];
        acc.x += v.x * w;
        acc.y += v.y * w;
    }
    *(float2*)&agg[(size_t)wid * DIM + coff] = acc;
}

// ---------------- bf16 helpers (hardware cvt) ----------------

__device__ __forceinline__ short bf16h(float f) {
    return __builtin_bit_cast(short, __float2bfloat16(f));  // HW RTNE cvt
}
__device__ __forceinline__ float bf16f(short h) {
    return __bfloat162float(__builtin_bit_cast(__hip_bfloat16, h));
}

// W[k][c] (128x128 f32) x3 -> Wt_hi[c][k], Wt_lo[c][k] (bf16 split); 3 weights fused
__global__ __launch_bounds__(256) void k_wprep3(
        const float* __restrict__ W1, const float* __restrict__ W2,
        const float* __restrict__ W3,
        unsigned short* __restrict__ hi1, unsigned short* __restrict__ lo1,
        unsigned short* __restrict__ hi2, unsigned short* __restrict__ lo2,
        unsigned short* __restrict__ hi3, unsigned short* __restrict__ lo3) {
    int m = blockIdx.x >> 6;               // 64 blocks per matrix
    int i = (blockIdx.x & 63) * 256 + threadIdx.x;  // 16384 per matrix
    const float* W = (m == 0) ? W1 : (m == 1) ? W2 : W3;
    unsigned short* hi = (m == 0) ? hi1 : (m == 1) ? hi2 : hi3;
    unsigned short* lo = (m == 0) ? lo1 : (m == 1) ? lo2 : lo3;
    int k = i >> 7, c = i & 127;
    float w = W[i];
    short h = bf16h(w);
    short l = bf16h(w - bf16f(h));
    hi[c * DIM + k] = (unsigned short)h;
    lo[c * DIM + k] = (unsigned short)l;
}

// ---------------- MFMA matmul + bias + relu (LDS-staged A, B-frag reuse) ----------------
// out[r][:] = relu(A[r][:] @ W + b); 3-term bf16 split A@W ~= Ah@Wh + Al@Wh + Ah@Wl
// Block: 64 rows. Phase 1: stage A as bf16 hi/lo in LDS (convert once).
// Phase 2: wave owns 2 col-tiles; B-frags in registers, reused across 4 row-tiles.
// mfma_f32_16x16x32_bf16: A row=lane&15, k=(lane>>4)*8+j ; C col=lane&15, row=(lane>>4)*4+reg

__global__ __launch_bounds__(256) void k_mm_mfma(
        const float* __restrict__ A, const unsigned short* __restrict__ wt_hi,
        const unsigned short* __restrict__ wt_lo, const float* __restrict__ bias,
        float* __restrict__ out, int n) {
    __shared__ unsigned short sAh[64 * SSTR];  // 17408 B
    __shared__ unsigned short sAl[64 * SSTR];  // 17408 B
    int tid = threadIdx.x;
    int wave = tid >> 6, lane = tid & 63;
    int r0b = blockIdx.x * 64;

    // ---- phase 1: stage 64 A rows as bf16 hi/lo ----
    // inst j: 256 lanes read contiguous float4 -> 16 KB coalesced
    {
        int subrow = tid >> 5;          // 0..7
        int colb = (tid & 31) * 4;      // element col 0..124
        const float4* A4 = (const float4*)A;
#pragma unroll
        for (int j = 0; j < 8; j++) {
            int row = j * 8 + subrow;
            int rowg = r0b + row;
            int rowc = rowg < n ? rowg : (n - 1);
            float4 v = A4[(size_t)rowc * 32 + (colb >> 2)];
            short h0 = bf16h(v.x), h1 = bf16h(v.y), h2 = bf16h(v.z), h3 = bf16h(v.w);
            short l0 = bf16h(v.x - bf16f(h0));
            short l1 = bf16h(v.y - bf16f(h1));
            short l2 = bf16h(v.z - bf16f(h2));
            short l3 = bf16h(v.w - bf16f(h3));
            ushort4 hv = {(unsigned short)h0, (unsigned short)h1,
                          (unsigned short)h2, (unsigned short)h3};
            ushort4 lv = {(unsigned short)l0, (unsigned short)l1,
                          (unsigned short)l2, (unsigned short)l3};
            *(ushort4*)&sAh[row * SSTR + colb] = hv;
            *(ushort4*)&sAl[row * SSTR + colb] = lv;
        }
    }
    __syncthreads();

    // ---- phase 2: MFMA, wave = 2 col-tiles x 4 row-tiles ----
    int lrow = lane & 15;   // A-frag row within tile / C col index
    int lk = lane >> 4;     // k-group 0..3
    bool full = (r0b + 64 <= n);

#pragma unroll
    for (int cti = 0; cti < 2; cti++) {
        int ct = wave * 2 + cti;
        int col = ct * 16 + lrow;
        const unsigned short* bh_base = wt_hi + (size_t)col * DIM + lk * 8;
        const unsigned short* bl_base = wt_lo + (size_t)col * DIM + lk * 8;
        s16x8 bh[4], bl[4];
#pragma unroll
        for (int ks = 0; ks < 4; ks++) {
            bh[ks] = *(const s16x8*)(bh_base + ks * 32);
            bl[ks] = *(const s16x8*)(bl_base + ks * 32);
        }
        float bcol = bias[col];

#pragma unroll
        for (int rt = 0; rt < 4; rt++) {
            const unsigned short* ah_base = &sAh[(rt * 16 + lrow) * SSTR + lk * 8];
            const unsigned short* al_base = &sAl[(rt * 16 + lrow) * SSTR + lk * 8];
            s16x8 ah[4], al[4];
#pragma unroll
            for (int ks = 0; ks < 4; ks++) {
                ah[ks] = *(const s16x8*)(ah_base + ks * 32);
                al[ks] = *(const s16x8*)(al_base + ks * 32);
            }
            f32x4 c = {0.f, 0.f, 0.f, 0.f};
#pragma unroll
            for (int ks = 0; ks < 4; ks++) {
                c = __builtin_amdgcn_mfma_f32_16x16x32_bf16(ah[ks], bh[ks], c, 0, 0, 0);
                c = __builtin_amdgcn_mfma_f32_16x16x32_bf16(al[ks], bh[ks], c, 0, 0, 0);
                c = __builtin_amdgcn_mfma_f32_16x16x32_bf16(ah[ks], bl[ks], c, 0, 0, 0);
            }
            int rbase = r0b + rt * 16 + lk * 4;
            if (full) {
#pragma unroll
                for (int reg = 0; reg < 4; reg++) {
                    float v = c[reg] + bcol;
                    out[(size_t)(rbase + reg) * DIM + col] = v > 0.f ? v : 0.f;
                }
            } else {
#pragma unroll
                for (int reg = 0; reg < 4; reg++) {
                    if (rbase + reg < n) {
                        float v = c[reg] + bcol;
                        out[(size_t)(rbase + reg) * DIM + col] = v > 0.f ? v : 0.f;
                    }
                }
            }
        }
    }
}

// ---------------- global mean pool: two-phase, device-filling ----------------

__global__ __launch_bounds__(256) void k_pool_part(const float* __restrict__ h,
        const int* __restrict__ batch, float* __restrict__ part, int n) {
    int g = blockIdx.x >> 4, s = blockIdx.x & 15;
    int lo = 0, hi = n;
    while (lo < hi) { int m = (lo + hi) >> 1; if (batch[m] < g) lo = m + 1; else hi = m; }
    int start = lo;
    int lo2 = start, hi2 = n;
    while (lo2 < hi2) { int m = (lo2 + hi2) >> 1; if (batch[m] < g + 1) lo2 = m + 1; else hi2 = m; }
    int end = lo2;

    int t = threadIdx.x;
    int wave = t >> 6, lane = t & 63;
    float2 acc = {0.f, 0.f};
    for (int r = start + s + 16 * wave; r < end; r += 64) {
        float2 v = *(const float2*)&h[(size_t)r * DIM + lane * 2];
        acc.x += v.x; acc.y += v.y;
    }
    __shared__ float2 red[4][64];
    red[wave][lane] = acc;
    __syncthreads();
    if (t < 64) {
        float2 s0 = red[0][t], s1 = red[1][t], s2 = red[2][t], s3 = red[3][t];
        float2 o;
        o.x = s0.x + s1.x + s2.x + s3.x;
        o.y = s0.y + s1.y + s2.y + s3.y;
        *(float2*)&part[(size_t)blockIdx.x * DIM + t * 2] = o;
    }
}

__global__ __launch_bounds__(128) void k_pool_fin(const float* __restrict__ part,
        const int* __restrict__ batch, float* __restrict__ out, int n) {
    int g = blockIdx.x, c = threadIdx.x;
    int lo = 0, hi = n;
    while (lo < hi) { int m = (lo + hi) >> 1; if (batch[m] < g) lo = m + 1; else hi = m; }
    int start = lo;
    int lo2 = start, hi2 = n;
    while (lo2 < hi2) { int m = (lo2 + hi2) >> 1; if (batch[m] < g + 1) lo2 = m + 1; else hi2 = m; }
    int end = lo2;

    float s = 0.f;
#pragma unroll
    for (int k = 0; k < 16; k++) s += part[(size_t)(g * 16 + k) * DIM + c];
    float cnt = (float)(end - start);
    cnt = cnt > 1.f ? cnt : 1.f;
    out[g * DIM + c] = s / cnt;
}

// ---------------- launch ----------------

extern "C" void kernel_launch(void* const* d_in, const int* in_sizes, int n_in,
                              void* d_out, int out_size, void* d_ws, size_t ws_size,
                              hipStream_t stream) {
    const float* x  = (const float*)d_in[0];
    const int*   ei = (const int*)d_in[1];
    const int*   batch = (const int*)d_in[2];
    const float* W1 = (const float*)d_in[3];
    const float* b1 = (const float*)d_in[4];
    const float* W2 = (const float*)d_in[5];
    const float* b2 = (const float*)d_in[6];
    const float* W3 = (const float*)d_in[7];
    const float* b3 = (const float*)d_in[8];

    int n = in_sizes[0] / DIM;  // 50000
    int e = in_sizes[1] / 2;    // 800000
    const int* erow = ei;       // sources
    const int* ecol = ei + e;   // targets
    int e4 = e / 4;             // 200000 (e divisible by 4)
    int nb = (n + 255) / 256;   // 196 scan blocks (<=256 required)

    char* ws = (char*)d_ws;
    size_t off = 0;
    auto alloc = [&](size_t bytes) -> void* {
        void* p = (void*)(ws + off);
        off += (bytes + 255) & ~(size_t)255;
        return p;
    };
    float* dis     = (float*)alloc((size_t)n * 4);
    int*   rowptr  = (int*)alloc((size_t)(n + 1) * 4);
    int*   csr_src = (int*)alloc((size_t)e * 4);
    float* agg     = (float*)alloc((size_t)n * DIM * 4);
    float* bufA    = (float*)alloc((size_t)n * DIM * 4);
    float* bufB    = (float*)alloc((size_t)n * DIM * 4);
    unsigned short* wt_hi1 = (unsigned short*)alloc(DIM * DIM * 2);
    unsigned short* wt_lo1 = (unsigned short*)alloc(DIM * DIM * 2);
    unsigned short* wt_hi2 = (unsigned short*)alloc(DIM * DIM * 2);
    unsigned short* wt_lo2 = (unsigned short*)alloc(DIM * DIM * 2);
    unsigned short* wt_hi3 = (unsigned short*)alloc(DIM * DIM * 2);
    unsigned short* wt_lo3 = (unsigned short*)alloc(DIM * DIM * 2);
    float* part    = (float*)alloc((size_t)1024 * DIM * 4);  // pool partials
    // transient CSR-build arrays overlap bufA (bufA first written in layer-1 mm)
    int* cnt    = (int*)bufA;
    int* cursor = ((int*)bufA) + n;
    int* bsum   = ((int*)bufA) + 2 * n;
    int* bbase  = ((int*)bufA) + 2 * n + 256;

    // ---- CSR build (once; edge_index is layer-invariant) ----
    hipMemsetAsync(cnt, 0, (size_t)n * 4, stream);
    k_count4<<<(e4 + 255) / 256, 256, 0, stream>>>((const int4*)ecol, cnt, e4);
    k_bsum<<<nb, 256, 0, stream>>>(cnt, bsum, n);
    k_bscan<<<1, 256, 0, stream>>>(bsum, bbase, nb);
    k_bfinal<<<nb, 256, 0, stream>>>(cnt, bbase, rowptr, cursor, dis, n, e);
    k_fill4<<<(e4 + 255) / 256, 256, 0, stream>>>((const int4*)erow, (const int4*)ecol,
                                                  cursor, csr_src, e4);

    // ---- weight prep (transposed bf16 hi/lo, all 3 fused) ----
    k_wprep3<<<192, 256, 0, stream>>>(W1, W2, W3, wt_hi1, wt_lo1, wt_hi2, wt_lo2,
                                      wt_hi3, wt_lo3);

    dim3 aggGrid(((size_t)n * 64 + 255) / 256);
    dim3 mmGrid((n + 63) / 64);

    // layer 1
    k_gcn_agg<<<aggGrid, 256, 0, stream>>>(x, csr_src, rowptr, dis, agg, n);
    k_mm_mfma<<<mmGrid, 256, 0, stream>>>(agg, wt_hi1, wt_lo1, b1, bufA, n);
    // layer 2
    k_gcn_agg<<<aggGrid, 256, 0, stream>>>(bufA, csr_src, rowptr, dis, agg, n);
    k_mm_mfma<<<mmGrid, 256, 0, stream>>>(agg, wt_hi2, wt_lo2, b2, bufB, n);
    // layer 3
    k_gcn_agg<<<aggGrid, 256, 0, stream>>>(bufB, csr_src, rowptr, dis, agg, n);
    k_mm_mfma<<<mmGrid, 256, 0, stream>>>(agg, wt_hi3, wt_lo3, b3, bufA, n);

    // global mean pool (two-phase, batch sorted -> binary-searched ranges)
    k_pool_part<<<1024, 256, 0, stream>>>(bufA, batch, part, n);
    k_pool_fin<<<N_GRAPHS, 128, 0, stream>>>(part, batch, (float*)d_out, n);
}

// Round 10
// 351.676 us; speedup vs baseline: 1.6850x; 1.0197x over previous
//
#include <hip/hip_runtime.h>
#include <hip/hip_bf16.h>

#define DIM 128
#define N_GRAPHS 64
#define SSTR 136  // LDS row stride in shorts (272 B): 2-way bank aliasing only (free)

typedef __attribute__((ext_vector_type(4))) float f32x4;
typedef __attribute__((ext_vector_type(8))) short s16x8;

// ---------------- degree / CSR precompute ----------------

__global__ void k_count4(const int4* __restrict__ col4, int* __restrict__ cnt, int e4) {
    int i = blockIdx.x * blockDim.x + threadIdx.x;
    if (i < e4) {
        int4 c = col4[i];
        atomicAdd(&cnt[c.x], 1);
        atomicAdd(&cnt[c.y], 1);
        atomicAdd(&cnt[c.z], 1);
        atomicAdd(&cnt[c.w], 1);
    }
}

__global__ __launch_bounds__(256) void k_bsum(const int* __restrict__ cnt,
                                              int* __restrict__ bsum, int n) {
    __shared__ int s[256];
    int t = threadIdx.x;
    int i = blockIdx.x * 256 + t;
    s[t] = (i < n) ? cnt[i] : 0;
    __syncthreads();
    for (int o = 128; o > 0; o >>= 1) {
        if (t < o) s[t] += s[t + o];
        __syncthreads();
    }
    if (t == 0) bsum[blockIdx.x] = s[0];
}

__global__ __launch_bounds__(256) void k_bscan(const int* __restrict__ bsum,
                                               int* __restrict__ bbase, int nb) {
    __shared__ int s[256];
    int t = threadIdx.x;
    int v = (t < nb) ? bsum[t] : 0;
    s[t] = v;
    __syncthreads();
    for (int o = 1; o < 256; o <<= 1) {
        int u = (t >= o) ? s[t - o] : 0;
        __syncthreads();
        s[t] += u;
        __syncthreads();
    }
    if (t < nb) bbase[t] = s[t] - v;  // exclusive
}

// also emits dis[i] = rsqrt(1 + degree) (self loop included)
__global__ __launch_bounds__(256) void k_bfinal(const int* __restrict__ cnt,
        const int* __restrict__ bbase, int* __restrict__ rowptr,
        int* __restrict__ cursor, float* __restrict__ dis, int n, int e) {
    __shared__ int s[256];
    int t = threadIdx.x;
    int i = blockIdx.x * 256 + t;
    int v = (i < n) ? cnt[i] : 0;
    s[t] = v;
    __syncthreads();
    for (int o = 1; o < 256; o <<= 1) {
        int u = (t >= o) ? s[t - o] : 0;
        __syncthreads();
        s[t] += u;
        __syncthreads();
    }
    if (i < n) {
        int excl = s[t] - v + bbase[blockIdx.x];
        rowptr[i] = excl;
        cursor[i] = excl;
        dis[i] = rsqrtf(1.0f + (float)v);
        if (i == n - 1) rowptr[n] = e;
    }
}

// fill pass 1: compute ranks via atomics, write positions COALESCED
__global__ void k_pos4(const int4* __restrict__ col4, int* __restrict__ cursor,
                       int4* __restrict__ pos4, int e4) {
    int i = blockIdx.x * blockDim.x + threadIdx.x;
    if (i >= e4) return;
    int4 c = col4[i];
    int4 p;
    p.x = atomicAdd(&cursor[c.x], 1);
    p.y = atomicAdd(&cursor[c.y], 1);
    p.z = atomicAdd(&cursor[c.z], 1);
    p.w = atomicAdd(&cursor[c.w], 1);
    pos4[i] = p;  // coalesced 16B store
}

// fill pass 2: pure scatter, no atomic dependency -> full MLP
__global__ void k_scat4(const int4* __restrict__ row4, const int4* __restrict__ pos4,
                        int* __restrict__ csr_src, int e4) {
    int i = blockIdx.x * blockDim.x + threadIdx.x;
    if (i >= e4) return;
    int4 r = row4[i];
    int4 p = pos4[i];
    csr_src[p.x] = r.x;
    csr_src[p.y] = r.y;
    csr_src[p.z] = r.z;
    csr_src[p.w] = r.w;
}

// ---------------- aggregation: gather form, 2 nodes per wave ----------------
// lane l owns columns [2l, 2l+1]; two independent accumulator chains (nodes 2w, 2w+1)
// -> 8 row-gathers in flight in the joint loop; all branches wave-uniform.

__global__ __launch_bounds__(256) void k_gcn_agg(const float* __restrict__ in,
        const int* __restrict__ csr_src, const int* __restrict__ rowptr,
        const float* __restrict__ dis, float* __restrict__ agg, int n) {
    int wave_id = (blockIdx.x * blockDim.x + threadIdx.x) >> 6;
    int lane = threadIdx.x & 63;
    const int coff = lane * 2;
    int wid0 = wave_id * 2;
    if (wid0 >= n) return;
    int wid1 = wid0 + 1;
    bool hasB = (wid1 < n);

    float dA = dis[wid0];
    float2 accA = *(const float2*)&in[(size_t)wid0 * DIM + coff];
    float ddA = dA * dA;
    accA.x *= ddA; accA.y *= ddA;
    int pA = rowptr[wid0], pA1 = rowptr[wid0 + 1];

    float dB = 0.f;
    float2 accB = {0.f, 0.f};
    int pB = 0, pB1 = 0;
    if (hasB) {
        dB = dis[wid1];
        accB = *(const float2*)&in[(size_t)wid1 * DIM + coff];
        float ddB = dB * dB;
        accB.x *= ddB; accB.y *= ddB;
        pB = pA1; pB1 = rowptr[wid1 + 1];
    }

    // joint main loop: 4 edges per node per iteration (8 gathers in flight)
    while (pA + 3 < pA1 && pB + 3 < pB1) {
        int a0 = csr_src[pA], a1 = csr_src[pA + 1], a2 = csr_src[pA + 2], a3 = csr_src[pA + 3];
        int b0 = csr_src[pB], b1 = csr_src[pB + 1], b2 = csr_src[pB + 2], b3 = csr_src[pB + 3];
        float wa0 = dA * dis[a0], wa1 = dA * dis[a1], wa2 = dA * dis[a2], wa3 = dA * dis[a3];
        float wb0 = dB * dis[b0], wb1 = dB * dis[b1], wb2 = dB * dis[b2], wb3 = dB * dis[b3];
        float2 va0 = *(const float2*)&in[(size_t)a0 * DIM + coff];
        float2 va1 = *(const float2*)&in[(size_t)a1 * DIM + coff];
        float2 va2 = *(const float2*)&in[(size_t)a2 * DIM + coff];
        float2 va3 = *(const float2*)&in[(size_t)a3 * DIM + coff];
        float2 vb0 = *(const float2*)&in[(size_t)b0 * DIM + coff];
        float2 vb1 = *(const float2*)&in[(size_t)b1 * DIM + coff];
        float2 vb2 = *(const float2*)&in[(size_t)b2 * DIM + coff];
        float2 vb3 = *(const float2*)&in[(size_t)b3 * DIM + coff];
        accA.x += va0.x * wa0; accA.y += va0.y * wa0;
        accA.x += va1.x * wa1; accA.y += va1.y * wa1;
        accA.x += va2.x * wa2; accA.y += va2.y * wa2;
        accA.x += va3.x * wa3; accA.y += va3.y * wa3;
        accB.x += vb0.x * wb0; accB.y += vb0.y * wb0;
        accB.x += vb1.x * wb1; accB.y += vb1.y * wb1;
        accB.x += vb2.x * wb2; accB.y += vb2.y * wb2;
        accB.x += vb3.x * wb3; accB.y += vb3.y * wb3;
        pA += 4; pB += 4;
    }
    // drain A
    for (; pA + 3 < pA1; pA += 4) {
        int a0 = csr_src[pA], a1 = csr_src[pA + 1], a2 = csr_src[pA + 2], a3 = csr_src[pA + 3];
        float wa0 = dA * dis[a0], wa1 = dA * dis[a1], wa2 = dA * dis[a2], wa3 = dA * dis[a3];
        float2 va0 = *(const float2*)&in[(size_t)a0 * DIM + coff];
        float2 va1 = *(const float2*)&in[(size_t)a1 * DIM + coff];
        float2 va2 = *(const float2*)&in[(size_t)a2 * DIM + coff];
        float2 va3 = *(const float2*)&in[(size_t)a3 * DIM + coff];
        accA.x += va0.x * wa0; accA.y += va0.y * wa0;
        accA.x += va1.x * wa1; accA.y += va1.y * wa1;
        accA.x += va2.x * wa2; accA.y += va2.y * wa2;
        accA.x += va3.x * wa3; accA.y += va3.y * wa3;
    }
    for (; pA < pA1; pA++) {
        int s = csr_src[pA];
        float w = dA * dis[s];
        float2 v = *(const float2*)&in[(size_t)s * DIM + coff];
        accA.x += v.x * w; accA.y += v.y * w;
    }
    *(float2*)&agg[(size_t)wid0 * DIM + coff] = accA;
    // drain B
    if (hasB) {
        for (; pB + 3 < pB1; pB += 4) {
            int b0 = csr_src[pB], b1 = csr_src[pB + 1], b2 = csr_src[pB + 2], b3 = csr_src[pB + 3];
            float wb0 = dB * dis[b0], wb1 = dB * dis[b1], wb2 = dB * dis[b2], wb3 = dB * dis[b3];
            float2 vb0 = *(const float2*)&in[(size_t)b0 * DIM + coff];
            float2 vb1 = *(const float2*)&in[(size_t)b1 * DIM + coff];
            float2 vb2 = *(const float2*)&in[(size_t)b2 * DIM + coff];
            float2 vb3 = *(const float2*)&in[(size_t)b3 * DIM + coff];
            accB.x += vb0.x * wb0; accB.y += vb0.y * wb0;
            accB.x += vb1.x * wb1; accB.y += vb1.y * wb1;
            accB.x += vb2.x * wb2; accB.y += vb2.y * wb2;
            accB.x += vb3.x * wb3; accB.y += vb3.y * wb3;
        }
        for (; pB < pB1; pB++) {
            int s = csr_src[pB];
            float w = dB * dis[s];
            float2 v = *(const float2*)&in[(size_t)s * DIM + coff];
            accB.x += v.x * w; accB.y += v.y * w;
        }
        *(float2*)&agg[(size_t)wid1 * DIM + coff] = accB;
    }
}

// ---------------- bf16 helpers (hardware cvt) ----------------

__device__ __forceinline__ short bf16h(float f) {
    return __builtin_bit_cast(short, __float2bfloat16(f));  // HW RTNE cvt
}
__device__ __forceinline__ float bf16f(short h) {
    return __bfloat162float(__builtin_bit_cast(__hip_bfloat16, h));
}

// W[k][c] (128x128 f32) x3 -> Wt_hi[c][k], Wt_lo[c][k] (bf16 split); 3 weights fused
__global__ __launch_bounds__(256) void k_wprep3(
        const float* __restrict__ W1, const float* __restrict__ W2,
        const float* __restrict__ W3,
        unsigned short* __restrict__ hi1, unsigned short* __restrict__ lo1,
        unsigned short* __restrict__ hi2, unsigned short* __restrict__ lo2,
        unsigned short* __restrict__ hi3, unsigned short* __restrict__ lo3) {
    int m = blockIdx.x >> 6;               // 64 blocks per matrix
    int i = (blockIdx.x & 63) * 256 + threadIdx.x;  // 16384 per matrix
    const float* W = (m == 0) ? W1 : (m == 1) ? W2 : W3;
    unsigned short* hi = (m == 0) ? hi1 : (m == 1) ? hi2 : hi3;
    unsigned short* lo = (m == 0) ? lo1 : (m == 1) ? lo2 : lo3;
    int k = i >> 7, c = i & 127;
    float w = W[i];
    short h = bf16h(w);
    short l = bf16h(w - bf16f(h));
    hi[c * DIM + k] = (unsigned short)h;
    lo[c * DIM + k] = (unsigned short)l;
}

// ---------------- MFMA matmul + bias + relu (LDS-staged A, B-frag reuse) ----------------

__global__ __launch_bounds__(256) void k_mm_mfma(
        const float* __restrict__ A, const unsigned short* __restrict__ wt_hi,
        const unsigned short* __restrict__ wt_lo, const float* __restrict__ bias,
        float* __restrict__ out, int n) {
    __shared__ unsigned short sAh[64 * SSTR];  // 17408 B
    __shared__ unsigned short sAl[64 * SSTR];  // 17408 B
    int tid = threadIdx.x;
    int wave = tid >> 6, lane = tid & 63;
    int r0b = blockIdx.x * 64;

    // ---- phase 1: stage 64 A rows as bf16 hi/lo ----
    {
        int subrow = tid >> 5;          // 0..7
        int colb = (tid & 31) * 4;      // element col 0..124
        const float4* A4 = (const float4*)A;
#pragma unroll
        for (int j = 0; j < 8; j++) {
            int row = j * 8 + subrow;
            int rowg = r0b + row;
            int rowc = rowg < n ? rowg : (n - 1);
            float4 v = A4[(size_t)rowc * 32 + (colb >> 2)];
            short h0 = bf16h(v.x), h1 = bf16h(v.y), h2 = bf16h(v.z), h3 = bf16h(v.w);
            short l0 = bf16h(v.x - bf16f(h0));
            short l1 = bf16h(v.y - bf16f(h1));
            short l2 = bf16h(v.z - bf16f(h2));
            short l3 = bf16h(v.w - bf16f(h3));
            ushort4 hv = {(unsigned short)h0, (unsigned short)h1,
                          (unsigned short)h2, (unsigned short)h3};
            ushort4 lv = {(unsigned short)l0, (unsigned short)l1,
                          (unsigned short)l2, (unsigned short)l3};
            *(ushort4*)&sAh[row * SSTR + colb] = hv;
            *(ushort4*)&sAl[row * SSTR + colb] = lv;
        }
    }
    __syncthreads();

    // ---- phase 2: MFMA, wave = 2 col-tiles x 4 row-tiles ----
    int lrow = lane & 15;   // A-frag row within tile / C col index
    int lk = lane >> 4;     // k-group 0..3
    bool full = (r0b + 64 <= n);

#pragma unroll
    for (int cti = 0; cti < 2; cti++) {
        int ct = wave * 2 + cti;
        int col = ct * 16 + lrow;
        const unsigned short* bh_base = wt_hi + (size_t)col * DIM + lk * 8;
        const unsigned short* bl_base = wt_lo + (size_t)col * DIM + lk * 8;
        s16x8 bh[4], bl[4];
#pragma unroll
        for (int ks = 0; ks < 4; ks++) {
            bh[ks] = *(const s16x8*)(bh_base + ks * 32);
            bl[ks] = *(const s16x8*)(bl_base + ks * 32);
        }
        float bcol = bias[col];

#pragma unroll
        for (int rt = 0; rt < 4; rt++) {
            const unsigned short* ah_base = &sAh[(rt * 16 + lrow) * SSTR + lk * 8];
            const unsigned short* al_base = &sAl[(rt * 16 + lrow) * SSTR + lk * 8];
            s16x8 ah[4], al[4];
#pragma unroll
            for (int ks = 0; ks < 4; ks++) {
                ah[ks] = *(const s16x8*)(ah_base + ks * 32);
                al[ks] = *(const s16x8*)(al_base + ks * 32);
            }
            f32x4 c = {0.f, 0.f, 0.f, 0.f};
#pragma unroll
            for (int ks = 0; ks < 4; ks++) {
                c = __builtin_amdgcn_mfma_f32_16x16x32_bf16(ah[ks], bh[ks], c, 0, 0, 0);
                c = __builtin_amdgcn_mfma_f32_16x16x32_bf16(al[ks], bh[ks], c, 0, 0, 0);
                c = __builtin_amdgcn_mfma_f32_16x16x32_bf16(ah[ks], bl[ks], c, 0, 0, 0);
            }
            int rbase = r0b + rt * 16 + lk * 4;
            if (full) {
#pragma unroll
                for (int reg = 0; reg < 4; reg++) {
                    float v = c[reg] + bcol;
                    out[(size_t)(rbase + reg) * DIM + col] = v > 0.f ? v : 0.f;
                }
            } else {
#pragma unroll
                for (int reg = 0; reg < 4; reg++) {
                    if (rbase + reg < n) {
                        float v = c[reg] + bcol;
                        out[(size_t)(rbase + reg) * DIM + col] = v > 0.f ? v : 0.f;
                    }
                }
            }
        }
    }
}

// ---------------- global mean pool: two-phase, device-filling ----------------

__global__ __launch_bounds__(256) void k_pool_part(const float* __restrict__ h,
        const int* __restrict__ batch, float* __restrict__ part, int n) {
    int g = blockIdx.x >> 4, s = blockIdx.x & 15;
    int lo = 0, hi = n;
    while (lo < hi) { int m = (lo + hi) >> 1; if (batch[m] < g) lo = m + 1; else hi = m; }
    int start = lo;
    int lo2 = start, hi2 = n;
    while (lo2 < hi2) { int m = (lo2 + hi2) >> 1; if (batch[m] < g + 1) lo2 = m + 1; else hi2 = m; }
    int end = lo2;

    int t = threadIdx.x;
    int wave = t >> 6, lane = t & 63;
    float2 acc = {0.f, 0.f};
    for (int r = start + s + 16 * wave; r < end; r += 64) {
        float2 v = *(const float2*)&h[(size_t)r * DIM + lane * 2];
        acc.x += v.x; acc.y += v.y;
    }
    __shared__ float2 red[4][64];
    red[wave][lane] = acc;
    __syncthreads();
    if (t < 64) {
        float2 s0 = red[0][t], s1 = red[1][t], s2 = red[2][t], s3 = red[3][t];
        float2 o;
        o.x = s0.x + s1.x + s2.x + s3.x;
        o.y = s0.y + s1.y + s2.y + s3.y;
        *(float2*)&part[(size_t)blockIdx.x * DIM + t * 2] = o;
    }
}

__global__ __launch_bounds__(128) void k_pool_fin(const float* __restrict__ part,
        const int* __restrict__ batch, float* __restrict__ out, int n) {
    int g = blockIdx.x, c = threadIdx.x;
    int lo = 0, hi = n;
    while (lo < hi) { int m = (lo + hi) >> 1; if (batch[m] < g) lo = m + 1; else hi = m; }
    int start = lo;
    int lo2 = start, hi2 = n;
    while (lo2 < hi2) { int m = (lo2 + hi2) >> 1; if (batch[m] < g + 1) lo2 = m + 1; else hi2 = m; }
    int end = lo2;

    float s = 0.f;
#pragma unroll
    for (int k = 0; k < 16; k++) s += part[(size_t)(g * 16 + k) * DIM + c];
    float cnt = (float)(end - start);
    cnt = cnt > 1.f ? cnt : 1.f;
    out[g * DIM + c] = s / cnt;
}

// ---------------- launch ----------------

extern "C" void kernel_launch(void* const* d_in, const int* in_sizes, int n_in,
                              void* d_out, int out_size, void* d_ws, size_t ws_size,
                              hipStream_t stream) {
    const float* x  = (const float*)d_in[0];
    const int*   ei = (const int*)d_in[1];
    const int*   batch = (const int*)d_in[2];
    const float* W1 = (const float*)d_in[3];
    const float* b1 = (const float*)d_in[4];
    const float* W2 = (const float*)d_in[5];
    const float* b2 = (const float*)d_in[6];
    const float* W3 = (const float*)d_in[7];
    const float* b3 = (const float*)d_in[8];

    int n = in_sizes[0] / DIM;  // 50000
    int e = in_sizes[1] / 2;    // 800000
    const int* erow = ei;       // sources
    const int* ecol = ei + e;   // targets
    int e4 = e / 4;             // 200000 (e divisible by 4)
    int nb = (n + 255) / 256;   // 196 scan blocks (<=256 required)

    char* ws = (char*)d_ws;
    size_t off = 0;
    auto alloc = [&](size_t bytes) -> void* {
        void* p = (void*)(ws + off);
        off += (bytes + 255) & ~(size_t)255;
        return p;
    };
    float* dis     = (float*)alloc((size_t)n * 4);
    int*   rowptr  = (int*)alloc((size_t)(n + 1) * 4);
    int*   csr_src = (int*)alloc((size_t)e * 4);
    float* agg     = (float*)alloc((size_t)n * DIM * 4);
    float* bufA    = (float*)alloc((size_t)n * DIM * 4);
    float* bufB    = (float*)alloc((size_t)n * DIM * 4);
    unsigned short* wt_hi1 = (unsigned short*)alloc(DIM * DIM * 2);
    unsigned short* wt_lo1 = (unsigned short*)alloc(DIM * DIM * 2);
    unsigned short* wt_hi2 = (unsigned short*)alloc(DIM * DIM * 2);
    unsigned short* wt_lo2 = (unsigned short*)alloc(DIM * DIM * 2);
    unsigned short* wt_hi3 = (unsigned short*)alloc(DIM * DIM * 2);
    unsigned short* wt_lo3 = (unsigned short*)alloc(DIM * DIM * 2);
    float* part    = (float*)alloc((size_t)1024 * DIM * 4);  // pool partials
    int*   pos     = (int*)alloc((size_t)e * 4);             // fill ranks
    // transient CSR-build arrays overlap bufA (bufA first written in layer-1 mm)
    int* cnt    = (int*)bufA;
    int* cursor = ((int*)bufA) + n;
    int* bsum   = ((int*)bufA) + 2 * n;
    int* bbase  = ((int*)bufA) + 2 * n + 256;

    // ---- CSR build (once; edge_index is layer-invariant) ----
    hipMemsetAsync(cnt, 0, (size_t)n * 4, stream);
    k_count4<<<(e4 + 255) / 256, 256, 0, stream>>>((const int4*)ecol, cnt, e4);
    k_bsum<<<nb, 256, 0, stream>>>(cnt, bsum, n);
    k_bscan<<<1, 256, 0, stream>>>(bsum, bbase, nb);
    k_bfinal<<<nb, 256, 0, stream>>>(cnt, bbase, rowptr, cursor, dis, n, e);
    k_pos4<<<(e4 + 255) / 256, 256, 0, stream>>>((const int4*)ecol, cursor,
                                                 (int4*)pos, e4);
    k_scat4<<<(e4 + 255) / 256, 256, 0, stream>>>((const int4*)erow, (const int4*)pos,
                                                  csr_src, e4);

    // ---- weight prep (transposed bf16 hi/lo, all 3 fused) ----
    k_wprep3<<<192, 256, 0, stream>>>(W1, W2, W3, wt_hi1, wt_lo1, wt_hi2, wt_lo2,
                                      wt_hi3, wt_lo3);

    int nwaves = (n + 1) / 2;  // 2 nodes per wave
    dim3 aggGrid(((size_t)nwaves * 64 + 255) / 256);
    dim3 mmGrid((n + 63) / 64);

    // layer 1
    k_gcn_agg<<<aggGrid, 256, 0, stream>>>(x, csr_src, rowptr, dis, agg, n);
    k_mm_mfma<<<mmGrid, 256, 0, stream>>>(agg, wt_hi1, wt_lo1, b1, bufA, n);
    // layer 2
    k_gcn_agg<<<aggGrid, 256, 0, stream>>>(bufA, csr_src, rowptr, dis, agg, n);
    k_mm_mfma<<<mmGrid, 256, 0, stream>>>(agg, wt_hi2, wt_lo2, b2, bufB, n);
    // layer 3
    k_gcn_agg<<<aggGrid, 256, 0, stream>>>(bufB, csr_src, rowptr, dis, agg, n);
    k_mm_mfma<<<mmGrid, 256, 0, stream>>>(agg, wt_hi3, wt_lo3, b3, bufA, n);

    // global mean pool (two-phase, batch sorted -> binary-searched ranges)
    k_pool_part<<<1024, 256, 0, stream>>>(bufA, batch, part, n);
    k_pool_fin<<<N_GRAPHS, 128, 0, stream>>>(part, batch, (float*)d_out, n);
}

// Round 11
// 257.214 us; speedup vs baseline: 2.3038x; 1.3672x over previous
//
#include <hip/hip_runtime.h>
#include <hip/hip_bf16.h>

#define DIM 128
#define N_GRAPHS 64
#define SSTR 136  // LDS row stride in shorts (272 B): 2-way bank aliasing only (free)

typedef __attribute__((ext_vector_type(4))) float f32x4;
typedef __attribute__((ext_vector_type(8))) short s16x8;

// ---------------- bf16 helpers (hardware cvt) ----------------

__device__ __forceinline__ short bf16h(float f) {
    return __builtin_bit_cast(short, __float2bfloat16(f));  // HW RTNE cvt
}
__device__ __forceinline__ float bf16f(unsigned short h) {
    unsigned u = ((unsigned)h) << 16;
    return __builtin_bit_cast(float, u);
}

// ---------------- degree / CSR precompute ----------------
// one atomic pass: cnt accumulates degree, returned value is the edge's rank
__global__ void k_rank4(const int4* __restrict__ col4, int* __restrict__ cnt,
                        int4* __restrict__ pos4, int e4) {
    int i = blockIdx.x * blockDim.x + threadIdx.x;
    if (i >= e4) return;
    int4 c = col4[i];
    int4 p;
    p.x = atomicAdd(&cnt[c.x], 1);
    p.y = atomicAdd(&cnt[c.y], 1);
    p.z = atomicAdd(&cnt[c.z], 1);
    p.w = atomicAdd(&cnt[c.w], 1);
    pos4[i] = p;  // coalesced 16B store
}

__global__ __launch_bounds__(256) void k_bsum(const int* __restrict__ cnt,
                                              int* __restrict__ bsum, int n) {
    __shared__ int s[256];
    int t = threadIdx.x;
    int i = blockIdx.x * 256 + t;
    s[t] = (i < n) ? cnt[i] : 0;
    __syncthreads();
    for (int o = 128; o > 0; o >>= 1) {
        if (t < o) s[t] += s[t + o];
        __syncthreads();
    }
    if (t == 0) bsum[blockIdx.x] = s[0];
}

__global__ __launch_bounds__(256) void k_bscan(const int* __restrict__ bsum,
                                               int* __restrict__ bbase, int nb) {
    __shared__ int s[256];
    int t = threadIdx.x;
    int v = (t < nb) ? bsum[t] : 0;
    s[t] = v;
    __syncthreads();
    for (int o = 1; o < 256; o <<= 1) {
        int u = (t >= o) ? s[t - o] : 0;
        __syncthreads();
        s[t] += u;
        __syncthreads();
    }
    if (t < nb) bbase[t] = s[t] - v;  // exclusive
}

// rowptr + dis = rsqrt(1 + degree)
__global__ __launch_bounds__(256) void k_bfinal(const int* __restrict__ cnt,
        const int* __restrict__ bbase, int* __restrict__ rowptr,
        float* __restrict__ dis, int n, int e) {
    __shared__ int s[256];
    int t = threadIdx.x;
    int i = blockIdx.x * 256 + t;
    int v = (i < n) ? cnt[i] : 0;
    s[t] = v;
    __syncthreads();
    for (int o = 1; o < 256; o <<= 1) {
        int u = (t >= o) ? s[t - o] : 0;
        __syncthreads();
        s[t] += u;
        __syncthreads();
    }
    if (i < n) {
        rowptr[i] = s[t] - v + bbase[blockIdx.x];
        dis[i] = rsqrtf(1.0f + (float)v);
        if (i == n - 1) rowptr[n] = e;
    }
}

// scatter: csr position = rowptr[col] + rank; no atomic dependency
__global__ void k_scat4(const int4* __restrict__ row4, const int4* __restrict__ col4,
                        const int4* __restrict__ pos4, const int* __restrict__ rowptr,
                        int* __restrict__ csr_src, int e4) {
    int i = blockIdx.x * blockDim.x + threadIdx.x;
    if (i >= e4) return;
    int4 r = row4[i];
    int4 c = col4[i];
    int4 p = pos4[i];
    csr_src[rowptr[c.x] + p.x] = r.x;
    csr_src[rowptr[c.y] + p.y] = r.y;
    csr_src[rowptr[c.z] + p.z] = r.z;
    csr_src[rowptr[c.w] + p.w] = r.w;
}

// ---------------- x -> bf16 copy ----------------

__global__ void k_cvt(const float* __restrict__ x, unsigned short* __restrict__ xb,
                      int total4) {
    int i = blockIdx.x * blockDim.x + threadIdx.x;
    if (i >= total4) return;
    float4 v = ((const float4*)x)[i];
    ushort4 o = {(unsigned short)bf16h(v.x), (unsigned short)bf16h(v.y),
                 (unsigned short)bf16h(v.z), (unsigned short)bf16h(v.w)};
    ((ushort4*)xb)[i] = o;
}

// ---------------- aggregation: gather form on bf16 rows (256 B/row) ----------------
// one wave per node; lane l owns columns [2l, 2l+1]; f32 accumulate; f32 output.

__global__ __launch_bounds__(256) void k_gcn_agg_bf(const unsigned short* __restrict__ in,
        const int* __restrict__ csr_src, const int* __restrict__ rowptr,
        const float* __restrict__ dis, float* __restrict__ agg, int n) {
    int wid = (blockIdx.x * blockDim.x + threadIdx.x) >> 6;
    if (wid >= n) return;
    int lane = threadIdx.x & 63;
    const int coff = lane * 2;
    float d = dis[wid];
    float dd = d * d;  // self-loop weight
    ushort2 sv = *(const ushort2*)&in[(size_t)wid * DIM + coff];
    float2 acc = {bf16f(sv.x) * dd, bf16f(sv.y) * dd};
    int p = rowptr[wid], p1 = rowptr[wid + 1];
    for (; p + 3 < p1; p += 4) {
        int s0 = csr_src[p], s1 = csr_src[p + 1], s2 = csr_src[p + 2], s3 = csr_src[p + 3];
        float w0 = d * dis[s0], w1 = d * dis[s1], w2 = d * dis[s2], w3 = d * dis[s3];
        ushort2 v0 = *(const ushort2*)&in[(size_t)s0 * DIM + coff];
        ushort2 v1 = *(const ushort2*)&in[(size_t)s1 * DIM + coff];
        ushort2 v2 = *(const ushort2*)&in[(size_t)s2 * DIM + coff];
        ushort2 v3 = *(const ushort2*)&in[(size_t)s3 * DIM + coff];
        acc.x += bf16f(v0.x) * w0; acc.y += bf16f(v0.y) * w0;
        acc.x += bf16f(v1.x) * w1; acc.y += bf16f(v1.y) * w1;
        acc.x += bf16f(v2.x) * w2; acc.y += bf16f(v2.y) * w2;
        acc.x += bf16f(v3.x) * w3; acc.y += bf16f(v3.y) * w3;
    }
    for (; p < p1; p++) {
        int s = csr_src[p];
        float w = d * dis[s];
        ushort2 v = *(const ushort2*)&in[(size_t)s * DIM + coff];
        acc.x += bf16f(v.x) * w;
        acc.y += bf16f(v.y) * w;
    }
    *(float2*)&agg[(size_t)wid * DIM + coff] = acc;
}

// W[k][c] (128x128 f32) x3 -> Wt_hi[c][k], Wt_lo[c][k] (bf16 split); 3 weights fused
__global__ __launch_bounds__(256) void k_wprep3(
        const float* __restrict__ W1, const float* __restrict__ W2,
        const float* __restrict__ W3,
        unsigned short* __restrict__ hi1, unsigned short* __restrict__ lo1,
        unsigned short* __restrict__ hi2, unsigned short* __restrict__ lo2,
        unsigned short* __restrict__ hi3, unsigned short* __restrict__ lo3) {
    int m = blockIdx.x >> 6;               // 64 blocks per matrix
    int i = (blockIdx.x & 63) * 256 + threadIdx.x;  // 16384 per matrix
    const float* W = (m == 0) ? W1 : (m == 1) ? W2 : W3;
    unsigned short* hi = (m == 0) ? hi1 : (m == 1) ? hi2 : hi3;
    unsigned short* lo = (m == 0) ? lo1 : (m == 1) ? lo2 : lo3;
    int k = i >> 7, c = i & 127;
    float w = W[i];
    short h = bf16h(w);
    short l = bf16h(w - bf16f((unsigned short)h));
    hi[c * DIM + k] = (unsigned short)h;
    lo[c * DIM + k] = (unsigned short)l;
}

// ---------------- MFMA matmul + bias + relu (LDS-staged A, B-frag reuse) ----------------
// out (bf16) = relu(A[r][:] @ W + b); 3-term bf16 split A@W ~= Ah@Wh + Al@Wh + Ah@Wl

__global__ __launch_bounds__(256) void k_mm_mfma(
        const float* __restrict__ A, const unsigned short* __restrict__ wt_hi,
        const unsigned short* __restrict__ wt_lo, const float* __restrict__ bias,
        unsigned short* __restrict__ out, int n) {
    __shared__ unsigned short sAh[64 * SSTR];  // 17408 B
    __shared__ unsigned short sAl[64 * SSTR];  // 17408 B
    int tid = threadIdx.x;
    int wave = tid >> 6, lane = tid & 63;
    int r0b = blockIdx.x * 64;

    // ---- phase 1: stage 64 A rows as bf16 hi/lo ----
    {
        int subrow = tid >> 5;          // 0..7
        int colb = (tid & 31) * 4;      // element col 0..124
        const float4* A4 = (const float4*)A;
#pragma unroll
        for (int j = 0; j < 8; j++) {
            int row = j * 8 + subrow;
            int rowg = r0b + row;
            int rowc = rowg < n ? rowg : (n - 1);
            float4 v = A4[(size_t)rowc * 32 + (colb >> 2)];
            short h0 = bf16h(v.x), h1 = bf16h(v.y), h2 = bf16h(v.z), h3 = bf16h(v.w);
            short l0 = bf16h(v.x - bf16f((unsigned short)h0));
            short l1 = bf16h(v.y - bf16f((unsigned short)h1));
            short l2 = bf16h(v.z - bf16f((unsigned short)h2));
            short l3 = bf16h(v.w - bf16f((unsigned short)h3));
            ushort4 hv = {(unsigned short)h0, (unsigned short)h1,
                          (unsigned short)h2, (unsigned short)h3};
            ushort4 lv = {(unsigned short)l0, (unsigned short)l1,
                          (unsigned short)l2, (unsigned short)l3};
            *(ushort4*)&sAh[row * SSTR + colb] = hv;
            *(ushort4*)&sAl[row * SSTR + colb] = lv;
        }
    }
    __syncthreads();

    // ---- phase 2: MFMA, wave = 2 col-tiles x 4 row-tiles ----
    int lrow = lane & 15;   // A-frag row within tile / C col index
    int lk = lane >> 4;     // k-group 0..3
    bool full = (r0b + 64 <= n);

#pragma unroll
    for (int cti = 0; cti < 2; cti++) {
        int ct = wave * 2 + cti;
        int col = ct * 16 + lrow;
        const unsigned short* bh_base = wt_hi + (size_t)col * DIM + lk * 8;
        const unsigned short* bl_base = wt_lo + (size_t)col * DIM + lk * 8;
        s16x8 bh[4], bl[4];
#pragma unroll
        for (int ks = 0; ks < 4; ks++) {
            bh[ks] = *(const s16x8*)(bh_base + ks * 32);
            bl[ks] = *(const s16x8*)(bl_base + ks * 32);
        }
        float bcol = bias[col];

#pragma unroll
        for (int rt = 0; rt < 4; rt++) {
            const unsigned short* ah_base = &sAh[(rt * 16 + lrow) * SSTR + lk * 8];
            const unsigned short* al_base = &sAl[(rt * 16 + lrow) * SSTR + lk * 8];
            s16x8 ah[4], al[4];
#pragma unroll
            for (int ks = 0; ks < 4; ks++) {
                ah[ks] = *(const s16x8*)(ah_base + ks * 32);
                al[ks] = *(const s16x8*)(al_base + ks * 32);
            }
            f32x4 c = {0.f, 0.f, 0.f, 0.f};
#pragma unroll
            for (int ks = 0; ks < 4; ks++) {
                c = __builtin_amdgcn_mfma_f32_16x16x32_bf16(ah[ks], bh[ks], c, 0, 0, 0);
                c = __builtin_amdgcn_mfma_f32_16x16x32_bf16(al[ks], bh[ks], c, 0, 0, 0);
                c = __builtin_amdgcn_mfma_f32_16x16x32_bf16(ah[ks], bl[ks], c, 0, 0, 0);
            }
            int rbase = r0b + rt * 16 + lk * 4;
            if (full) {
#pragma unroll
                for (int reg = 0; reg < 4; reg++) {
                    float v = c[reg] + bcol;
                    v = v > 0.f ? v : 0.f;
                    out[(size_t)(rbase + reg) * DIM + col] = (unsigned short)bf16h(v);
                }
            } else {
#pragma unroll
                for (int reg = 0; reg < 4; reg++) {
                    if (rbase + reg < n) {
                        float v = c[reg] + bcol;
                        v = v > 0.f ? v : 0.f;
                        out[(size_t)(rbase + reg) * DIM + col] = (unsigned short)bf16h(v);
                    }
                }
            }
        }
    }
}

// ---------------- global mean pool: two-phase, device-filling, bf16 input ----------------

__global__ __launch_bounds__(256) void k_pool_part(const unsigned short* __restrict__ h,
        const int* __restrict__ batch, float* __restrict__ part, int n) {
    int g = blockIdx.x >> 4, s = blockIdx.x & 15;
    int lo = 0, hi = n;
    while (lo < hi) { int m = (lo + hi) >> 1; if (batch[m] < g) lo = m + 1; else hi = m; }
    int start = lo;
    int lo2 = start, hi2 = n;
    while (lo2 < hi2) { int m = (lo2 + hi2) >> 1; if (batch[m] < g + 1) lo2 = m + 1; else hi2 = m; }
    int end = lo2;

    int t = threadIdx.x;
    int wave = t >> 6, lane = t & 63;
    float2 acc = {0.f, 0.f};
    for (int r = start + s + 16 * wave; r < end; r += 64) {
        ushort2 v = *(const ushort2*)&h[(size_t)r * DIM + lane * 2];
        acc.x += bf16f(v.x); acc.y += bf16f(v.y);
    }
    __shared__ float2 red[4][64];
    red[wave][lane] = acc;
    __syncthreads();
    if (t < 64) {
        float2 s0 = red[0][t], s1 = red[1][t], s2 = red[2][t], s3 = red[3][t];
        float2 o;
        o.x = s0.x + s1.x + s2.x + s3.x;
        o.y = s0.y + s1.y + s2.y + s3.y;
        *(float2*)&part[(size_t)blockIdx.x * DIM + t * 2] = o;
    }
}

__global__ __launch_bounds__(128) void k_pool_fin(const float* __restrict__ part,
        const int* __restrict__ batch, float* __restrict__ out, int n) {
    int g = blockIdx.x, c = threadIdx.x;
    int lo = 0, hi = n;
    while (lo < hi) { int m = (lo + hi) >> 1; if (batch[m] < g) lo = m + 1; else hi = m; }
    int start = lo;
    int lo2 = start, hi2 = n;
    while (lo2 < hi2) { int m = (lo2 + hi2) >> 1; if (batch[m] < g + 1) lo2 = m + 1; else hi2 = m; }
    int end = lo2;

    float s = 0.f;
#pragma unroll
    for (int k = 0; k < 16; k++) s += part[(size_t)(g * 16 + k) * DIM + c];
    float cnt = (float)(end - start);
    cnt = cnt > 1.f ? cnt : 1.f;
    out[g * DIM + c] = s / cnt;
}

// ---------------- launch ----------------

extern "C" void kernel_launch(void* const* d_in, const int* in_sizes, int n_in,
                              void* d_out, int out_size, void* d_ws, size_t ws_size,
                              hipStream_t stream) {
    const float* x  = (const float*)d_in[0];
    const int*   ei = (const int*)d_in[1];
    const int*   batch = (const int*)d_in[2];
    const float* W1 = (const float*)d_in[3];
    const float* b1 = (const float*)d_in[4];
    const float* W2 = (const float*)d_in[5];
    const float* b2 = (const float*)d_in[6];
    const float* W3 = (const float*)d_in[7];
    const float* b3 = (const float*)d_in[8];

    int n = in_sizes[0] / DIM;  // 50000
    int e = in_sizes[1] / 2;    // 800000
    const int* erow = ei;       // sources
    const int* ecol = ei + e;   // targets
    int e4 = e / 4;             // 200000 (e divisible by 4)
    int nb = (n + 255) / 256;   // 196 scan blocks (<=256 required)

    char* ws = (char*)d_ws;
    size_t off = 0;
    auto alloc = [&](size_t bytes) -> void* {
        void* p = (void*)(ws + off);
        off += (bytes + 255) & ~(size_t)255;
        return p;
    };
    float* dis     = (float*)alloc((size_t)n * 4);
    int*   rowptr  = (int*)alloc((size_t)(n + 1) * 4);
    int*   csr_src = (int*)alloc((size_t)e * 4);
    float* agg     = (float*)alloc((size_t)n * DIM * 4);          // f32 agg output
    unsigned short* xb    = (unsigned short*)alloc((size_t)n * DIM * 2);  // x as bf16
    unsigned short* hbufA = (unsigned short*)alloc((size_t)n * DIM * 2);  // h bf16
    unsigned short* hbufB = (unsigned short*)alloc((size_t)n * DIM * 2);
    unsigned short* wt_hi1 = (unsigned short*)alloc(DIM * DIM * 2);
    unsigned short* wt_lo1 = (unsigned short*)alloc(DIM * DIM * 2);
    unsigned short* wt_hi2 = (unsigned short*)alloc(DIM * DIM * 2);
    unsigned short* wt_lo2 = (unsigned short*)alloc(DIM * DIM * 2);
    unsigned short* wt_hi3 = (unsigned short*)alloc(DIM * DIM * 2);
    unsigned short* wt_lo3 = (unsigned short*)alloc(DIM * DIM * 2);
    float* part    = (float*)alloc((size_t)1024 * DIM * 4);  // pool partials
    int*   pos     = (int*)alloc((size_t)e * 4);             // edge ranks
    // transient CSR-build arrays overlap agg (agg first written in layer-1 agg)
    int* cnt    = (int*)agg;
    int* bsum   = ((int*)agg) + n;
    int* bbase  = ((int*)agg) + n + 256;

    // ---- CSR build (once; edge_index is layer-invariant) ----
    hipMemsetAsync(cnt, 0, (size_t)n * 4, stream);
    k_rank4<<<(e4 + 255) / 256, 256, 0, stream>>>((const int4*)ecol, cnt, (int4*)pos, e4);
    k_bsum<<<nb, 256, 0, stream>>>(cnt, bsum, n);
    k_bscan<<<1, 256, 0, stream>>>(bsum, bbase, nb);
    k_bfinal<<<nb, 256, 0, stream>>>(cnt, bbase, rowptr, dis, n, e);
    k_scat4<<<(e4 + 255) / 256, 256, 0, stream>>>((const int4*)erow, (const int4*)ecol,
                                                  (const int4*)pos, rowptr, csr_src, e4);

    // ---- input cvt + weight prep ----
    int total4 = n * DIM / 4;
    k_cvt<<<(total4 + 255) / 256, 256, 0, stream>>>(x, xb, total4);
    k_wprep3<<<192, 256, 0, stream>>>(W1, W2, W3, wt_hi1, wt_lo1, wt_hi2, wt_lo2,
                                      wt_hi3, wt_lo3);

    dim3 aggGrid(((size_t)n * 64 + 255) / 256);
    dim3 mmGrid((n + 63) / 64);

    // layer 1
    k_gcn_agg_bf<<<aggGrid, 256, 0, stream>>>(xb, csr_src, rowptr, dis, agg, n);
    k_mm_mfma<<<mmGrid, 256, 0, stream>>>(agg, wt_hi1, wt_lo1, b1, hbufA, n);
    // layer 2
    k_gcn_agg_bf<<<aggGrid, 256, 0, stream>>>(hbufA, csr_src, rowptr, dis, agg, n);
    k_mm_mfma<<<mmGrid, 256, 0, stream>>>(agg, wt_hi2, wt_lo2, b2, hbufB, n);
    // layer 3
    k_gcn_agg_bf<<<aggGrid, 256, 0, stream>>>(hbufB, csr_src, rowptr, dis, agg, n);
    k_mm_mfma<<<mmGrid, 256, 0, stream>>>(agg, wt_hi3, wt_lo3, b3, hbufA, n);

    // global mean pool (two-phase, batch sorted -> binary-searched ranges)
    k_pool_part<<<1024, 256, 0, stream>>>(hbufA, batch, part, n);
    k_pool_fin<<<N_GRAPHS, 128, 0, stream>>>(part, batch, (float*)d_out, n);
}